// Round 13
// baseline (408.698 us; speedup 1.0000x reference)
//
#include <hip/hip_runtime.h>
#include <math.h>

#define NN 65536      // nodes
#define NE 524288     // edges
#define NG 256        // graphs (256 contiguous nodes each)
#define SLOPE 0.01f
#define CAP 131072    // worklist capacity per layer (typ. ~1k items)
#define LDP 40        // padded LDS row stride (elems) for a 32-k chunk

typedef __attribute__((ext_vector_type(8))) short s8v;   // 8 bf16 (4 VGPRs)
typedef __attribute__((ext_vector_type(4))) float f4v;   // 4 fp32 acc

__device__ __forceinline__ float lrelu(float v){ return v > 0.f ? v : SLOPE*v; }

__device__ __forceinline__ unsigned short f2bf(float f){
  unsigned u = __float_as_uint(f);
  u += 0x7FFF + ((u>>16)&1);          // round-to-nearest-even
  return (unsigned short)(u>>16);
}
__device__ __forceinline__ float bf2f(unsigned short b){
  return __uint_as_float(((unsigned)b)<<16);
}

// ---------- block reductions (256-thread blocks = 4 waves) ----------
__device__ __forceinline__ float blockMax4(float v, float* s4){
  #pragma unroll
  for(int o=32;o>0;o>>=1) v = fmaxf(v, __shfl_down(v, o, 64));
  int t = threadIdx.x;
  __syncthreads();
  if((t&63)==0) s4[t>>6] = v;
  __syncthreads();
  return fmaxf(fmaxf(s4[0], s4[1]), fmaxf(s4[2], s4[3]));
}
__device__ __forceinline__ float blockSum4(float v, float* s4){
  #pragma unroll
  for(int o=32;o>0;o>>=1) v += __shfl_down(v, o, 64);
  int t = threadIdx.x;
  __syncthreads();
  if((t&63)==0) s4[t>>6] = v;
  __syncthreads();
  return (s4[0]+s4[1])+(s4[2]+s4[3]);
}

// ---------- CSR build (by dst) ----------
__global__ __launch_bounds__(256) void k_count(const int* __restrict__ ei, int* __restrict__ deg){
  int e = blockIdx.x*256 + threadIdx.x;
  if(e < NE) atomicAdd(&deg[ei[NE + e]], 1);
}

__global__ __launch_bounds__(1024) void k_scan(const int* __restrict__ deg,
      int* __restrict__ offs, int* __restrict__ cursor){
  __shared__ int part[1024];
  int t = threadIdx.x;
  const int4* d4 = (const int4*)(deg + t*64);
  int4 buf[16];
  int s=0;
  #pragma unroll
  for(int i=0;i<16;i++){ buf[i]=d4[i]; s += buf[i].x+buf[i].y+buf[i].z+buf[i].w; }
  part[t]=s;
  __syncthreads();
  for(int off=1; off<1024; off<<=1){
    int v = (t>=off)? part[t-off] : 0;
    __syncthreads();
    part[t] += v;
    __syncthreads();
  }
  int run = (t==0)? 0 : part[t-1];
  #pragma unroll
  for(int i=0;i<16;i++){
    int4 d = buf[i];
    int4 o;
    o.x = run; run += d.x;
    o.y = run; run += d.y;
    o.z = run; run += d.z;
    o.w = run; run += d.w;
    ((int4*)(offs + t*64))[i] = o;
    ((int4*)(cursor + t*64))[i] = o;
  }
  if(t==1023) offs[NN] = run;
}

__global__ __launch_bounds__(256) void k_scatter(const int* __restrict__ ei,
      int* __restrict__ cursor, int* __restrict__ csr){
  int e = blockIdx.x*256 + threadIdx.x;
  if(e < NE){
    int d = ei[NE + e];
    int p = atomicAdd(&cursor[d], 1);
    csr[p] = ei[e];
  }
}

// ---------- conv0: agg[i] = max over in-edges of x[src], else 0 ----------
__global__ __launch_bounds__(256) void k_agg0(const float* __restrict__ x,
    const int* __restrict__ offs, const int* __restrict__ csr, float* __restrict__ agg0){
  int tid = blockIdx.x*256 + threadIdx.x;
  int node = tid>>4, q = tid&15;
  int e0 = offs[node], e1 = offs[node+1];
  float4 acc = make_float4(0.f,0.f,0.f,0.f);
  if(e0 < e1){
    acc = make_float4(-INFINITY,-INFINITY,-INFINITY,-INFINITY);
    const int last = e1 - 1;
    for(int e=e0; e<e1; e+=8){
      int si[8];
      #pragma unroll
      for(int u=0;u<8;u++){
        int ee = e+u; ee = ee<last? ee : last;
        si[u] = csr[ee];
      }
      float4 v[8];
      #pragma unroll
      for(int u=0;u<8;u++) v[u] = ((const float4*)x)[si[u]*16 + q];
      #pragma unroll
      for(int u=0;u<8;u++){
        acc.x=fmaxf(acc.x,v[u].x); acc.y=fmaxf(acc.y,v[u].y);
        acc.z=fmaxf(acc.z,v[u].z); acc.w=fmaxf(acc.w,v[u].w);
      }
    }
  }
  ((float4*)agg0)[node*16 + q] = acc;
}

// ---------- conv0 matmul on MFMA: cur0 = lrelu([agg0|x] @ [Wrel|Wroot]^T + b0) ----------
// fp32-equivalent via hi/mid/lo bf16 split (6 products; residual ~2^-24).
__global__ __launch_bounds__(256, 2) void k_conv0mm(
    const float* __restrict__ agg0, const float* __restrict__ x,
    const float* __restrict__ Wrel, const float* __restrict__ Wroot,
    const float* __restrict__ b0, float* __restrict__ cur,
    float* __restrict__ bnsum, float* __restrict__ bnsq){
  __shared__ unsigned short Ah[128*LDP], Am[128*LDP], Al[128*LDP];
  __shared__ unsigned short Wh[128*LDP], Wm[128*LDP], Wl[128*LDP];
  const int t = threadIdx.x;
  const int wave = t>>6, lane = t&63, lm = lane&15, quad = lane>>4;
  const int rowbase = (wave>>1)*64, colbase = (wave&1)*64;
  const int nbase = blockIdx.x*128;

  f4v acc[4][4];
  #pragma unroll
  for(int i=0;i<4;i++)
    #pragma unroll
    for(int j=0;j<4;j++) acc[i][j] = (f4v){0.f,0.f,0.f,0.f};

  #pragma unroll 1
  for(int ch=0; ch<4; ch++){
    const float* gA = (ch<2 ? agg0 : x);
    const float* gW = (ch<2 ? Wrel : Wroot);
    const int kq = (ch&1)*8;
    __syncthreads();
    #pragma unroll
    for(int i=0;i<4;i++){
      int idx = t + i*256;
      int row = idx>>3, k4 = idx&7;
      float4 va = ((const float4*)gA)[(size_t)(nbase+row)*16 + kq + k4];
      float4 vw = ((const float4*)gW)[(size_t)row*16 + kq + k4];
      unsigned long long ph=0, pm=0, pl=0, qh=0, qm=0, ql=0;
      float fa[4] = {va.x,va.y,va.z,va.w};
      float fw[4] = {vw.x,vw.y,vw.z,vw.w};
      #pragma unroll
      for(int e=0;e<4;e++){
        unsigned short h = f2bf(fa[e]);
        float r1 = fa[e]-bf2f(h);
        unsigned short m = f2bf(r1);
        unsigned short l = f2bf(r1-bf2f(m));
        ph |= (unsigned long long)h << (e*16);
        pm |= (unsigned long long)m << (e*16);
        pl |= (unsigned long long)l << (e*16);
        unsigned short h2 = f2bf(fw[e]);
        float r1w = fw[e]-bf2f(h2);
        unsigned short m2 = f2bf(r1w);
        unsigned short l2 = f2bf(r1w-bf2f(m2));
        qh |= (unsigned long long)h2 << (e*16);
        qm |= (unsigned long long)m2 << (e*16);
        ql |= (unsigned long long)l2 << (e*16);
      }
      int off = row*LDP + k4*4;
      *(unsigned long long*)&Ah[off] = ph;
      *(unsigned long long*)&Am[off] = pm;
      *(unsigned long long*)&Al[off] = pl;
      *(unsigned long long*)&Wh[off] = qh;
      *(unsigned long long*)&Wm[off] = qm;
      *(unsigned long long*)&Wl[off] = ql;
    }
    __syncthreads();
    s8v ah[4], amv[4], alv[4];
    #pragma unroll
    for(int rt=0;rt<4;rt++){
      int off = (rowbase + rt*16 + lm)*LDP + quad*8;
      ah[rt]  = *(const s8v*)&Ah[off];
      amv[rt] = *(const s8v*)&Am[off];
      alv[rt] = *(const s8v*)&Al[off];
    }
    #pragma unroll
    for(int ct=0;ct<4;ct++){
      int off = (colbase + ct*16 + lm)*LDP + quad*8;
      s8v bh = *(const s8v*)&Wh[off];
      s8v bm = *(const s8v*)&Wm[off];
      s8v bl = *(const s8v*)&Wl[off];
      #pragma unroll
      for(int rt=0;rt<4;rt++){
        acc[rt][ct] = __builtin_amdgcn_mfma_f32_16x16x32_bf16(ah[rt],  bh, acc[rt][ct], 0,0,0);
        acc[rt][ct] = __builtin_amdgcn_mfma_f32_16x16x32_bf16(ah[rt],  bm, acc[rt][ct], 0,0,0);
        acc[rt][ct] = __builtin_amdgcn_mfma_f32_16x16x32_bf16(amv[rt], bh, acc[rt][ct], 0,0,0);
        acc[rt][ct] = __builtin_amdgcn_mfma_f32_16x16x32_bf16(ah[rt],  bl, acc[rt][ct], 0,0,0);
        acc[rt][ct] = __builtin_amdgcn_mfma_f32_16x16x32_bf16(alv[rt], bh, acc[rt][ct], 0,0,0);
        acc[rt][ct] = __builtin_amdgcn_mfma_f32_16x16x32_bf16(amv[rt], bm, acc[rt][ct], 0,0,0);
      }
    }
  }

  float bj[4];
  #pragma unroll
  for(int ct=0;ct<4;ct++) bj[ct] = b0[colbase + ct*16 + lm];
  float cs[4]={0.f,0.f,0.f,0.f}, cq[4]={0.f,0.f,0.f,0.f};
  #pragma unroll
  for(int rt=0;rt<4;rt++){
    #pragma unroll
    for(int ct=0;ct<4;ct++){
      int col = colbase + ct*16 + lm;
      #pragma unroll
      for(int r=0;r<4;r++){
        int row = rowbase + rt*16 + quad*4 + r;
        float v = lrelu(acc[rt][ct][r] + bj[ct]);
        cur[(size_t)(nbase+row)*128 + col] = v;
        cs[ct]+=v; cq[ct]+=v*v;
      }
    }
  }
  #pragma unroll
  for(int o=16;o<64;o<<=1){
    #pragma unroll
    for(int ct=0;ct<4;ct++){
      cs[ct] += __shfl_xor(cs[ct], o, 64);
      cq[ct] += __shfl_xor(cq[ct], o, 64);
    }
  }
  __syncthreads();
  float* redS = (float*)Ah;
  float* redQ = (float*)Am;
  if(quad==0){
    #pragma unroll
    for(int ct=0;ct<4;ct++){
      int col = colbase + ct*16 + lm;
      redS[(wave>>1)*128 + col] = cs[ct];
      redQ[(wave>>1)*128 + col] = cq[ct];
    }
  }
  __syncthreads();
  if(t<128){
    atomicAdd(&bnsum[t], redS[t]+redS[128+t]);
    atomicAdd(&bnsq[t],  redQ[t]+redQ[128+t]);
  }
}

// ---------- one pass over cur0: scores for pool0, pool1, cls (affine fold) ----------
__global__ __launch_bounds__(256) void k_scores(const float* __restrict__ cur0,
    const float* __restrict__ bns0, const float* __restrict__ bnq0,
    const float* __restrict__ g0,
    const float* __restrict__ pw0, const float* __restrict__ pw1,
    const float* __restrict__ pwc,
    float* __restrict__ scores0, float* __restrict__ pre1, float* __restrict__ pre2){
  __shared__ __align__(16) float w[12][128];
  __shared__ float sc0s[128];
  const int t = threadIdx.x;
  if(t<128){
    float mu = bns0[t]*(1.0f/NN);
    float var = bnq0[t]*(1.0f/NN) - mu*mu;
    sc0s[t] = g0[t]*rsqrtf(var+1e-5f);
  }
  __syncthreads();
  for(int i=t;i<512;i+=256){
    int h=i>>7, j=i&127;
    float s = sc0s[j];
    w[h][j]   = pw0[i]*s;
    w[4+h][j] = pw1[i]*(0.5f*s);
    w[8+h][j] = pwc[i]*(0.25f*s);
  }
  __syncthreads();
  const int tid = blockIdx.x*256 + t;
  const int n = tid>>5, k = tid&31;
  float4 v = ((const float4*)cur0)[tid];
  float a[12];
  #pragma unroll
  for(int q=0;q<12;q++){
    float4 wv = *(const float4*)&w[q][k*4];
    a[q] = v.x*wv.x + v.y*wv.y + v.z*wv.z + v.w*wv.w;
  }
  #pragma unroll
  for(int o=16;o>0;o>>=1){
    #pragma unroll
    for(int q=0;q<12;q++) a[q] += __shfl_down(a[q], o, 32);
  }
  if(k==0){
    ((float4*)scores0)[n] = make_float4(a[0],a[1],a[2],a[3]);
    ((float4*)pre1)[n]    = make_float4(a[4],a[5],a[6],a[7]);
    ((float4*)pre2)[n]    = make_float4(a[8],a[9],a[10],a[11]);
  }
}

// ---------- pool select layer 0: wave-per-head, barrier-free ----------
__global__ __launch_bounds__(256) void k_poolselW(const float* __restrict__ scores,
    float minscore, float* __restrict__ sm4, int* __restrict__ cnt,
    int* __restrict__ wl, int* __restrict__ idxP){
  const int t = threadIdx.x, g = blockIdx.x;
  const int h = t>>6, l = t&63;
  const int n0 = g*256;
  float s[4];
  #pragma unroll
  for(int i=0;i<4;i++) s[i] = scores[(size_t)(n0 + l + i*64)*4 + h];
  float m = fmaxf(fmaxf(s[0],s[1]),fmaxf(s[2],s[3]));
  #pragma unroll
  for(int o=32;o>0;o>>=1) m = fmaxf(m, __shfl_xor(m, o, 64));
  float e[4], es=0.f;
  #pragma unroll
  for(int i=0;i<4;i++){ e[i]=expf(s[i]-m); es+=e[i]; }
  #pragma unroll
  for(int o=32;o>0;o>>=1) es += __shfl_xor(es, o, 64);
  float inv = 1.f/(es+1e-16f);
  float sm[4];
  float mx = -INFINITY;
  #pragma unroll
  for(int i=0;i<4;i++){ sm[i]=e[i]*inv; mx=fmaxf(mx,sm[i]); }
  #pragma unroll
  for(int o=32;o>0;o>>=1) mx = fmaxf(mx, __shfl_xor(mx, o, 64));
  float thr = fminf(mx - 1e-7f, minscore);
  #pragma unroll
  for(int i=0;i<4;i++){
    int n = n0 + l + i*64;
    sm4[(size_t)n*4 + h] = sm[i];
    int slot = -1;
    if(sm[i] > thr){
      int p = atomicAdd(cnt, 1);
      if(p < CAP){ slot = p; wl[p] = (h<<16) | n; }
    }
    idxP[(size_t)h*NN + n] = slot;
  }
}

// ---------- layer-0 GraphConv(max) on kept items (rows = bn0(cur0)) ----------
__global__ __launch_bounds__(256) void k_blockconv0(const float* __restrict__ cur0,
    const int* __restrict__ offs, const int* __restrict__ csr,
    const int* __restrict__ idxP, const float* __restrict__ sm4,
    const int* __restrict__ cnt, const int* __restrict__ wl,
    const float* __restrict__ Wrel, const float* __restrict__ Wroot,
    const float* __restrict__ bias,
    float* __restrict__ new1c, float* __restrict__ bnsum, float* __restrict__ bnsq,
    const float* __restrict__ bns0, const float* __restrict__ bnq0,
    const float* __restrict__ g0, const float* __restrict__ b0bn){
  __shared__ __align__(16) float aggs[8][128];
  __shared__ __align__(16) float xps[8][128];
  __shared__ __align__(16) float scv[128];
  __shared__ __align__(16) float ofv[128];
  const int t = threadIdx.x, grp = t>>5, lane = t&31;
  if(t<128){
    float mu = bns0[t]*(1.0f/NN);
    float var = bnq0[t]*(1.0f/NN) - mu*mu;
    float sv = g0[t]*rsqrtf(var+1e-5f);
    scv[t]=sv; ofv[t]=b0bn[t]-mu*sv;
  }
  __syncthreads();
  const float4 s4l = *(const float4*)&scv[lane*4];
  const float4 o4l = *(const float4*)&ofv[lane*4];
  int total = *cnt; if(total > CAP) total = CAP;
  for(int item = blockIdx.x*8 + grp; item < total; item += gridDim.x*8){
    const int wv = wl[item];
    const int h = wv>>16, n = wv & 0xFFFF;
    const size_t hn = (size_t)h*NN;
    const float smn = sm4[(size_t)n*4+h];
    const int e0 = offs[n], e1 = offs[n+1];
    float4 acc = make_float4(-INFINITY,-INFINITY,-INFINITY,-INFINITY);
    bool any = false;
    for(int e=e0;e<e1;e++){
      int s = csr[e];
      if(idxP[hn + s] >= 0){
        any = true;
        float sv = sm4[(size_t)s*4+h];
        float4 v = ((const float4*)cur0)[s*32 + lane];
        v.x = (v.x*s4l.x + o4l.x)*sv; v.y = (v.y*s4l.y + o4l.y)*sv;
        v.z = (v.z*s4l.z + o4l.z)*sv; v.w = (v.w*s4l.w + o4l.w)*sv;
        acc.x = fmaxf(acc.x, v.x); acc.y = fmaxf(acc.y, v.y);
        acc.z = fmaxf(acc.z, v.z); acc.w = fmaxf(acc.w, v.w);
      }
    }
    if(!any) acc = make_float4(0.f,0.f,0.f,0.f);
    *(float4*)&aggs[grp][lane*4] = acc;
    float4 xv = ((const float4*)cur0)[n*32 + lane];
    xv.x = (xv.x*s4l.x + o4l.x)*smn; xv.y = (xv.y*s4l.y + o4l.y)*smn;
    xv.z = (xv.z*s4l.z + o4l.z)*smn; xv.w = (xv.w*s4l.w + o4l.w)*smn;
    *(float4*)&xps[grp][lane*4] = xv;
    // half-wave group: LDS write->read program-ordered within the wave
    const float* Wr = Wrel  + (size_t)(h*32+lane)*128;
    const float* Wo = Wroot + (size_t)(h*32+lane)*128;
    float o = bias[h*32+lane];
    for(int k=0;k<32;k++){
      float4 a  = *(const float4*)&aggs[grp][k*4];
      float4 xx = *(const float4*)&xps[grp][k*4];
      float4 wr = ((const float4*)Wr)[k];
      float4 wo = ((const float4*)Wo)[k];
      o += a.x*wr.x + a.y*wr.y + a.z*wr.z + a.w*wr.w;
      o += xx.x*wo.x + xx.y*wo.y + xx.z*wo.z + xx.w*wo.w;
    }
    o = lrelu(o);
    new1c[(size_t)item*32 + lane] = o;
    atomicAdd(&bnsum[h*32+lane], o);
    atomicAdd(&bnsq[h*32+lane], o*o);
  }
}

// ---------- pool select layer 1: patch phase + wave-per-head select ----------
__global__ __launch_bounds__(256) void k_poolsel1(
    const float* __restrict__ pre1, float* __restrict__ pre2,
    const int* __restrict__ cnt0, const int* __restrict__ wl0,
    const float* __restrict__ new1c,
    const float* __restrict__ bnsA, const float* __restrict__ bnqA,
    const float* __restrict__ g1v,
    const float* __restrict__ pw1, const float* __restrict__ pwc,
    float minscore, float* __restrict__ sm4out,
    int* __restrict__ cnt1, int* __restrict__ wl1, int* __restrict__ idx1P){
  __shared__ float s1s[128];
  __shared__ __align__(16) float w1s[4][128];
  __shared__ __align__(16) float wcs[4][128];
  __shared__ float patch1[256][4];
  const int t = threadIdx.x, g = blockIdx.x;
  if(t<128){
    float mu = bnsA[t]*(1.0f/NN);
    float var = bnqA[t]*(1.0f/NN) - mu*mu;
    s1s[t] = g1v[t]*rsqrtf(var+1e-5f);
  }
  for(int i=t;i<512;i+=256){ w1s[i>>7][i&127]=pw1[i]; wcs[i>>7][i&127]=pwc[i]; }
  #pragma unroll
  for(int h=0;h<4;h++) patch1[t][h]=0.f;
  __syncthreads();
  int total0 = *cnt0; if(total0 > CAP) total0 = CAP;
  for(int i=t; i<total0; i+=256){
    int wv = wl0[i];
    int n = wv & 0xFFFF, hp = wv>>16;
    if((n>>8)==g){
      int nl = n & 255;
      float d[4]={0.f,0.f,0.f,0.f}, d2[4]={0.f,0.f,0.f,0.f};
      for(int l=0;l<32;l++){
        int j = hp*32+l;
        float base = new1c[(size_t)i*32+l] * s1s[j];
        #pragma unroll
        for(int h=0;h<4;h++){ d[h]+=base*w1s[h][j]; d2[h]+=base*wcs[h][j]; }
      }
      #pragma unroll
      for(int h=0;h<4;h++){
        atomicAdd(&patch1[nl][h], 0.25f*d[h]);
        atomicAdd(&pre2[n*4+h], 0.125f*d2[h]);
      }
    }
  }
  __syncthreads();
  const int h = t>>6, l = t&63;
  const int n0 = g*256;
  float s[4];
  #pragma unroll
  for(int i=0;i<4;i++){
    int nl = l + i*64;
    s[i] = pre1[(size_t)(n0+nl)*4 + h] + patch1[nl][h];
  }
  float m = fmaxf(fmaxf(s[0],s[1]),fmaxf(s[2],s[3]));
  #pragma unroll
  for(int o=32;o>0;o>>=1) m = fmaxf(m, __shfl_xor(m, o, 64));
  float e[4], es=0.f;
  #pragma unroll
  for(int i=0;i<4;i++){ e[i]=expf(s[i]-m); es+=e[i]; }
  #pragma unroll
  for(int o=32;o>0;o>>=1) es += __shfl_xor(es, o, 64);
  float inv = 1.f/(es+1e-16f);
  float sm[4];
  float mx = -INFINITY;
  #pragma unroll
  for(int i=0;i<4;i++){ sm[i]=e[i]*inv; mx=fmaxf(mx,sm[i]); }
  #pragma unroll
  for(int o=32;o>0;o>>=1) mx = fmaxf(mx, __shfl_xor(mx, o, 64));
  float thr = fminf(mx - 1e-7f, minscore);
  #pragma unroll
  for(int i=0;i<4;i++){
    int n = n0 + l + i*64;
    sm4out[(size_t)n*4 + h] = sm[i];
    int slot = -1;
    if(sm[i] > thr){
      int p = atomicAdd(cnt1, 1);
      if(p < CAP){ slot = p; wl1[p] = (h<<16) | n; }
    }
    idx1P[(size_t)h*NN + n] = slot;
  }
}

// ---------- layer-1 GraphConv(max): rows reconstructed from cur0 + new1c ----------
__global__ __launch_bounds__(256) void k_blockconv1(const float* __restrict__ cur0,
    const int* __restrict__ offs, const int* __restrict__ csr,
    const int* __restrict__ idx0P, const float* __restrict__ new1c,
    const int* __restrict__ idx1P, const float* __restrict__ sm41,
    const int* __restrict__ cnt1, const int* __restrict__ wl1,
    const float* __restrict__ Wrel, const float* __restrict__ Wroot,
    const float* __restrict__ bias,
    float* __restrict__ new2c, float* __restrict__ bnsum, float* __restrict__ bnsq,
    const float* __restrict__ bns0, const float* __restrict__ bnq0,
    const float* __restrict__ g0, const float* __restrict__ b0bn,
    const float* __restrict__ bnsA, const float* __restrict__ bnqA,
    const float* __restrict__ g1v, const float* __restrict__ b1v){
  __shared__ __align__(16) float aggs[8][128];
  __shared__ __align__(16) float xps[8][128];
  __shared__ __align__(16) float sc0s[128], of0s[128], s1s[128], o1s[128];
  const int t = threadIdx.x, grp = t>>5, lane = t&31;
  if(t<128){
    float mu = bns0[t]*(1.0f/NN);
    float var = bnq0[t]*(1.0f/NN) - mu*mu;
    float sv = g0[t]*rsqrtf(var+1e-5f);
    sc0s[t]=sv; of0s[t]=b0bn[t]-mu*sv;
    float mu1 = bnsA[t]*(1.0f/NN);
    float var1 = bnqA[t]*(1.0f/NN) - mu1*mu1;
    float s1 = g1v[t]*rsqrtf(var1+1e-5f);
    s1s[t]=s1; o1s[t]=b1v[t]-mu1*s1;
  }
  __syncthreads();
  const float4 s0l = *(const float4*)&sc0s[lane*4];
  const float4 o0l = *(const float4*)&of0s[lane*4];
  const float4 s1l = *(const float4*)&s1s[lane*4];
  const float4 o1l = *(const float4*)&o1s[lane*4];
  const int hb = lane>>3;
  const size_t hbn = (size_t)hb*NN;
  int total = *cnt1; if(total > CAP) total = CAP;
  for(int item = blockIdx.x*8 + grp; item < total; item += gridDim.x*8){
    const int wv = wl1[item];
    const int h = wv>>16, n = wv & 0xFFFF;
    const size_t hn = (size_t)h*NN;
    const float smn = sm41[(size_t)n*4+h];
    const int e0 = offs[n], e1 = offs[n+1];
    float4 acc = make_float4(-INFINITY,-INFINITY,-INFINITY,-INFINITY);
    bool any = false;
    for(int e=e0;e<e1;e++){
      int s = csr[e];
      if(idx1P[hn + s] >= 0){
        any = true;
        float sv = sm41[(size_t)s*4+h];
        float4 c0 = ((const float4*)cur0)[s*32 + lane];
        float4 v;
        v.x = 0.5f*(s0l.x*c0.x+o0l.x) + 0.25f*o1l.x;
        v.y = 0.5f*(s0l.y*c0.y+o0l.y) + 0.25f*o1l.y;
        v.z = 0.5f*(s0l.z*c0.z+o0l.z) + 0.25f*o1l.z;
        v.w = 0.5f*(s0l.w*c0.w+o0l.w) + 0.25f*o1l.w;
        int i0 = idx0P[hbn + s];
        if(i0 >= 0){
          float4 nv = ((const float4*)(new1c + (size_t)i0*32))[lane&7];
          v.x += 0.25f*s1l.x*nv.x; v.y += 0.25f*s1l.y*nv.y;
          v.z += 0.25f*s1l.z*nv.z; v.w += 0.25f*s1l.w*nv.w;
        }
        v.x*=sv; v.y*=sv; v.z*=sv; v.w*=sv;
        acc.x = fmaxf(acc.x, v.x); acc.y = fmaxf(acc.y, v.y);
        acc.z = fmaxf(acc.z, v.z); acc.w = fmaxf(acc.w, v.w);
      }
    }
    if(!any) acc = make_float4(0.f,0.f,0.f,0.f);
    *(float4*)&aggs[grp][lane*4] = acc;
    {
      float4 c0 = ((const float4*)cur0)[n*32 + lane];
      float4 v;
      v.x = 0.5f*(s0l.x*c0.x+o0l.x) + 0.25f*o1l.x;
      v.y = 0.5f*(s0l.y*c0.y+o0l.y) + 0.25f*o1l.y;
      v.z = 0.5f*(s0l.z*c0.z+o0l.z) + 0.25f*o1l.z;
      v.w = 0.5f*(s0l.w*c0.w+o0l.w) + 0.25f*o1l.w;
      int i0 = idx0P[hbn + n];
      if(i0 >= 0){
        float4 nv = ((const float4*)(new1c + (size_t)i0*32))[lane&7];
        v.x += 0.25f*s1l.x*nv.x; v.y += 0.25f*s1l.y*nv.y;
        v.z += 0.25f*s1l.z*nv.z; v.w += 0.25f*s1l.w*nv.w;
      }
      v.x*=smn; v.y*=smn; v.z*=smn; v.w*=smn;
      *(float4*)&xps[grp][lane*4] = v;
    }
    const float* Wr = Wrel  + (size_t)(h*32+lane)*128;
    const float* Wo = Wroot + (size_t)(h*32+lane)*128;
    float o = bias[h*32+lane];
    for(int k=0;k<32;k++){
      float4 a  = *(const float4*)&aggs[grp][k*4];
      float4 xx = *(const float4*)&xps[grp][k*4];
      float4 wr = ((const float4*)Wr)[k];
      float4 wo = ((const float4*)Wo)[k];
      o += a.x*wr.x + a.y*wr.y + a.z*wr.z + a.w*wr.w;
      o += xx.x*wo.x + xx.y*wo.y + xx.z*wo.z + xx.w*wo.w;
    }
    o = lrelu(o);
    new2c[(size_t)item*32 + lane] = o;
    atomicAdd(&bnsum[h*32+lane], o);
    atomicAdd(&bnsq[h*32+lane], o*o);
  }
}

// ---------- cls: block per (graph,class); wave-parallel gate matvecs (r13) ----------
__global__ __launch_bounds__(256) void k_cls2(const float* __restrict__ cur0,
    const int* __restrict__ idx0P, const float* __restrict__ new1c,
    const int* __restrict__ idx1P, const float* __restrict__ new2c,
    const float* __restrict__ pre2, const int* __restrict__ cnt1,
    const int* __restrict__ wl1, const float* __restrict__ pwc,
    const float* __restrict__ bns0, const float* __restrict__ bnq0,
    const float* __restrict__ g0, const float* __restrict__ b0bn,
    const float* __restrict__ bnsA, const float* __restrict__ bnqA,
    const float* __restrict__ g1v, const float* __restrict__ b1v,
    const float* __restrict__ bnsB, const float* __restrict__ bnqB,
    const float* __restrict__ g2v, const float* __restrict__ b2v,
    const float* __restrict__ gW1, const float* __restrict__ gb1,
    const float* __restrict__ gW2, const float* __restrict__ gb2,
    const float* __restrict__ fW1, const float* __restrict__ fb1,
    const float* __restrict__ fW2, const float* __restrict__ fb2,
    float* __restrict__ yws, int* __restrict__ gcnt, float* __restrict__ out){
  __shared__ float red[4];
  __shared__ float sc0s[128], of0s[128], s1s[128], o1s[128], s2s[128], o2s[128];
  __shared__ float wc[128];
  __shared__ float patch[256];
  __shared__ int keptL[256];
  __shared__ float keptS[256];
  __shared__ float gateL[256];
  __shared__ __align__(16) float xkW[4][128];   // per-wave row buffer
  __shared__ __align__(16) float pooled[128];
  __shared__ int nkept;
  const int t = threadIdx.x, wave = t>>6, lane = t&63;
  const int g = blockIdx.x >> 2, c = blockIdx.x & 3;
  if(t<128){
    float mu = bns0[t]*(1.0f/NN);
    float var = bnq0[t]*(1.0f/NN) - mu*mu;
    float sv = g0[t]*rsqrtf(var+1e-5f);
    sc0s[t]=sv; of0s[t]=b0bn[t]-mu*sv;
    float mu1 = bnsA[t]*(1.0f/NN);
    float var1 = bnqA[t]*(1.0f/NN) - mu1*mu1;
    float s1 = g1v[t]*rsqrtf(var1+1e-5f);
    s1s[t]=s1; o1s[t]=b1v[t]-mu1*s1;
    float mu2 = bnsB[t]*(1.0f/NN);
    float var2 = bnqB[t]*(1.0f/NN) - mu2*mu2;
    float s2 = g2v[t]*rsqrtf(var2+1e-5f);
    s2s[t]=s2; o2s[t]=b2v[t]-mu2*s2;
    wc[t] = pwc[c*128+t];
  }
  patch[t]=0.f;
  __syncthreads();
  int total1 = *cnt1; if(total1 > CAP) total1 = CAP;
  for(int i=t; i<total1; i+=256){
    int wv = wl1[i];
    int n = wv & 0xFFFF, hp = wv>>16;
    if((n>>8)==g){
      float d=0.f;
      for(int l=0;l<32;l++){
        int j = hp*32+l;
        d += new2c[(size_t)i*32+l]*s2s[j]*wc[j];
      }
      atomicAdd(&patch[n&255], 0.25f*d);
    }
  }
  __syncthreads();
  const int n = g*256 + t;
  float sc = pre2[n*4 + c] + patch[t];
  float m = blockMax4(sc, red);
  float e = expf(sc-m);
  float ssum = blockSum4(e, red);
  float sm = e/(ssum+1e-16f);
  float smax = blockMax4(sm, red);
  float thr = fminf(smax - 1e-7f, 0.8f);
  if(t==0) nkept = 0;
  __syncthreads();
  if(sm > thr){
    int p = atomicAdd(&nkept,1);
    keptL[p]=t; keptS[p]=sm;
  }
  __syncthreads();
  const int K = nkept;
  // gate matvecs: wave-parallel, no block barriers inside
  for(int k=wave; k<K; k+=4){
    int ln = keptL[k]; float sv = keptS[k];
    int nn = g*256 + ln;
    if(lane<32){
      float4 c0 = ((const float4*)cur0)[nn*32 + lane];
      float4 s0l = *(const float4*)&sc0s[lane*4];
      float4 o0l = *(const float4*)&of0s[lane*4];
      float4 s1l = *(const float4*)&s1s[lane*4];
      float4 o1l = *(const float4*)&o1s[lane*4];
      float4 s2l = *(const float4*)&s2s[lane*4];
      float4 o2l = *(const float4*)&o2s[lane*4];
      int hb = lane>>3;
      float4 v1;
      v1.x = 0.5f*(s0l.x*c0.x+o0l.x) + 0.25f*o1l.x;
      v1.y = 0.5f*(s0l.y*c0.y+o0l.y) + 0.25f*o1l.y;
      v1.z = 0.5f*(s0l.z*c0.z+o0l.z) + 0.25f*o1l.z;
      v1.w = 0.5f*(s0l.w*c0.w+o0l.w) + 0.25f*o1l.w;
      int i0 = idx0P[(size_t)hb*NN + nn];
      if(i0 >= 0){
        float4 nv = ((const float4*)(new1c + (size_t)i0*32))[lane&7];
        v1.x += 0.25f*s1l.x*nv.x; v1.y += 0.25f*s1l.y*nv.y;
        v1.z += 0.25f*s1l.z*nv.z; v1.w += 0.25f*s1l.w*nv.w;
      }
      float4 v2;
      v2.x = 0.5f*v1.x + 0.25f*o2l.x;
      v2.y = 0.5f*v1.y + 0.25f*o2l.y;
      v2.z = 0.5f*v1.z + 0.25f*o2l.z;
      v2.w = 0.5f*v1.w + 0.25f*o2l.w;
      int i1 = idx1P[(size_t)hb*NN + nn];
      if(i1 >= 0){
        float4 nv = ((const float4*)(new2c + (size_t)i1*32))[lane&7];
        v2.x += 0.25f*s2l.x*nv.x; v2.y += 0.25f*s2l.y*nv.y;
        v2.z += 0.25f*s2l.z*nv.z; v2.w += 0.25f*s2l.w*nv.w;
      }
      v2.x*=sv; v2.y*=sv; v2.z*=sv; v2.w*=sv;
      *(float4*)&xkW[wave][lane*4] = v2;
    }
    // wave-ordered LDS write->read (compiler emits lgkmcnt wait; same wave)
    float gp = 0.f;
    #pragma unroll
    for(int jj=0;jj<2;jj++){
      int j = lane + jj*64;
      const float* W = gW1 + (size_t)c*16384 + (size_t)j*128;
      float a = gb1[c*128+j];
      for(int f=0;f<32;f++){
        float4 xv = *(const float4*)&xkW[wave][f*4];
        float4 wv = ((const float4*)W)[f];
        a += xv.x*wv.x + xv.y*wv.y + xv.z*wv.z + xv.w*wv.w;
      }
      gp += lrelu(a) * gW2[c*128+j];
    }
    #pragma unroll
    for(int o=32;o>0;o>>=1) gp += __shfl_xor(gp, o, 64);
    if(lane==0) gateL[k] = gp + gb2[c];
  }
  __syncthreads();
  float gv = (t<K)? gateL[t] : -INFINITY;
  float gm = blockMax4(gv, red);
  float ge = (t<K)? expf(gv-gm) : 0.f;
  float gsum = blockSum4(ge, red);
  if(t<K) gateL[t] = ge/(gsum+1e-16f);
  __syncthreads();
  if(t<128){
    int hb = t>>5, l = t&31;
    float acc = 0.f;
    for(int k=0;k<K;k++){
      int nn = g*256 + keptL[k];
      float c0 = cur0[(size_t)nn*128 + t];
      float v1 = 0.5f*(sc0s[t]*c0 + of0s[t]) + 0.25f*o1s[t];
      int i0 = idx0P[(size_t)hb*NN + nn];
      if(i0 >= 0) v1 += 0.25f*s1s[t]*new1c[(size_t)i0*32 + l];
      float v2 = 0.5f*v1 + 0.25f*o2s[t];
      int i1 = idx1P[(size_t)hb*NN + nn];
      if(i1 >= 0) v2 += 0.25f*s2s[t]*new2c[(size_t)i1*32 + l];
      acc += gateL[k]*keptS[k]*v2;
    }
    pooled[t]=acc;
  }
  __syncthreads();
  float part2=0.f;
  if(t<128){
    const float* F = fW1 + (size_t)c*16384 + (size_t)t*128;
    float a = fb1[c*128+t];
    for(int f=0;f<32;f++){
      float4 xv = *(const float4*)&pooled[f*4];
      float4 wv = ((const float4*)F)[f];
      a += xv.x*wv.x + xv.y*wv.y + xv.z*wv.z + xv.w*wv.w;
    }
    part2 = lrelu(a) * fW2[c*128+t];
  }
  float ysum = blockSum4(part2, red);
  if(t==0){
    yws[g*4+c] = ysum + fb2[c];
    __threadfence();
    int old = atomicAdd(&gcnt[g], 1);
    if(old == 3){
      __threadfence();
      volatile float* yv = yws + g*4;
      float y0=yv[0], y1=yv[1], y2=yv[2], y3=yv[3];
      float mm = fmaxf(fmaxf(y0,y1), fmaxf(y2,y3));
      float ll = logf(expf(y0-mm)+expf(y1-mm)+expf(y2-mm)+expf(y3-mm));
      out[g*4+0]=y0-mm-ll; out[g*4+1]=y1-mm-ll;
      out[g*4+2]=y2-mm-ll; out[g*4+3]=y3-mm-ll;
    }
  }
}

extern "C" void kernel_launch(void* const* d_in, const int* in_sizes, int n_in,
                              void* d_out, int out_size, void* d_ws, size_t ws_size,
                              hipStream_t stream){
  (void)in_sizes; (void)n_in; (void)out_size; (void)ws_size;
  const float* x     = (const float*)d_in[0];
  const int*   ei    = (const int*)d_in[1];
  const float* Wrel0 = (const float*)d_in[3];
  const float* Wroot0= (const float*)d_in[4];
  const float* b0    = (const float*)d_in[5];
  const float* bn0g  = (const float*)d_in[6];
  const float* bn0b  = (const float*)d_in[7];
  const float* bpw   = (const float*)d_in[8];
  const float* bWrel = (const float*)d_in[9];
  const float* bWroot= (const float*)d_in[10];
  const float* bbv   = (const float*)d_in[11];
  const float* bbng  = (const float*)d_in[12];
  const float* bbnb  = (const float*)d_in[13];
  const float* cpw   = (const float*)d_in[14];
  const float* gW1   = (const float*)d_in[15];
  const float* gb1   = (const float*)d_in[16];
  const float* gW2   = (const float*)d_in[17];
  const float* gb2   = (const float*)d_in[18];
  const float* fW1   = (const float*)d_in[19];
  const float* fb1   = (const float*)d_in[20];
  const float* fW2   = (const float*)d_in[21];
  const float* fb2   = (const float*)d_in[22];

  char* ws = (char*)d_ws;
  float* cur0  = (float*)(ws + 0);                  // 33.55 MB
  float* new1c = (float*)(ws + 33554432ull);        // 16.78 MB (CAP*32 floats)
  float* new2c = (float*)(ws + 50331648ull);        // 16.78 MB (aliases agg0)
  float* agg0  = new2c;                             // dead before new2c written
  int*   csr   = (int*)(ws + 67108864ull);          // 2 MB
  float* scores0=(float*)(ws + 69206016ull);        // 1 MB (sm4_0 aliases)
  float* sm40  = scores0;
  float* pre1  = (float*)(ws + 70254592ull);        // 1 MB (sm4_1 aliases)
  float* sm41  = pre1;
  float* pre2  = (float*)(ws + 71303168ull);        // 1 MB
  int*   wl0   = (int*)(ws + 72351744ull);          // 512 KB
  int*   wl1   = (int*)(ws + 72876032ull);          // 512 KB
  int*   offs  = (int*)(ws + 73400320ull);          // 256 KB + 4
  int*   cursor= (int*)(ws + 73666560ull);          // 256 KB
  int*   idx0P = (int*)(ws + 73928704ull);          // 1 MB (4 planes, always written)
  int*   idx1P = (int*)(ws + 74977280ull);          // 1 MB
  char*  Z     = ws + 76025856ull;                  // zero-init region
  int*   deg   = (int*)Z;                           // 256 KB
  float* bnsum0= (float*)(Z + 262144);
  float* bnsq0 = (float*)(Z + 262656);
  float* bnA   = (float*)(Z + 263168);
  float* bqA   = (float*)(Z + 263680);
  float* bnB   = (float*)(Z + 264192);
  float* bqB   = (float*)(Z + 264704);
  int*   cnt0  = (int*)(Z + 265216);
  int*   cnt1  = (int*)(Z + 265220);
  float* yws   = (float*)(Z + 266240);              // 4 KB
  int*   gcnt  = (int*)(Z + 270336);                // 1 KB

  hipMemsetAsync(Z, 0, 271360, stream);

  // CSR by dst
  k_count  <<<2048,256,0,stream>>>(ei, deg);
  k_scan   <<<1,1024,0,stream>>>(deg, offs, cursor);
  k_scatter<<<2048,256,0,stream>>>(ei, cursor, csr);

  // conv0 -> lrelu (+ fused bn0 stats; MFMA hi/mid/lo bf16 split)
  k_agg0    <<<4096,256,0,stream>>>(x, offs, csr, agg0);
  k_conv0mm <<<512,256,0,stream>>>(agg0, x, Wrel0, Wroot0, b0, cur0, bnsum0, bnsq0);

  // single pass: scores for pool0 + pre-scores for pool1/cls
  k_scores<<<8192,256,0,stream>>>(cur0, bnsum0, bnsq0, bn0g,
                                  bpw, bpw + 512, cpw, scores0, pre1, pre2);

  // pool layer 0 select (wave-per-head, barrier-free)
  k_poolselW<<<256,256,0,stream>>>(scores0, 0.7f, sm40, cnt0, wl0, idx0P);

  // layer-0 conv on kept items
  k_blockconv0<<<256,256,0,stream>>>(cur0, offs, csr, idx0P, sm40, cnt0, wl0,
                                     bWrel, bWroot, bbv, new1c, bnA, bqA,
                                     bnsum0, bnsq0, bn0g, bn0b);

  // pool layer 1 select (patches pre1 with layer-1 corr, pre2 partially)
  k_poolsel1<<<256,256,0,stream>>>(pre1, pre2, cnt0, wl0, new1c,
                                   bnA, bqA, bbng,
                                   bpw + 512, cpw,
                                   0.7f, sm41, cnt1, wl1, idx1P);

  // layer-1 conv on kept items (rows reconstructed)
  k_blockconv1<<<256,256,0,stream>>>(cur0, offs, csr, idx0P, new1c,
                                     idx1P, sm41, cnt1, wl1,
                                     bWrel + 16384, bWroot + 16384, bbv + 128,
                                     new2c, bnB, bqB,
                                     bnsum0, bnsq0, bn0g, bn0b,
                                     bnA, bqA, bbng, bbnb);

  // classification heads + fused per-graph log_softmax (last-block pattern)
  k_cls2<<<1024,256,0,stream>>>(cur0, idx0P, new1c, idx1P, new2c,
                                pre2, cnt1, wl1, cpw,
                                bnsum0, bnsq0, bn0g, bn0b,
                                bnA, bqA, bbng, bbnb,
                                bnB, bqB, bbng + 128, bbnb + 128,
                                gW1, gb1, gW2, gb2, fW1, fb1, fW2, fb2,
                                yws, gcnt, (float*)d_out);
}

// Round 14
// 371.311 us; speedup vs baseline: 1.1007x; 1.1007x over previous
//
#include <hip/hip_runtime.h>
#include <math.h>

#define NN 65536      // nodes
#define NE 524288     // edges
#define NG 256        // graphs (256 contiguous nodes each)
#define SLOPE 0.01f
#define CAP 131072    // worklist capacity per layer (typ. ~1k items)
#define LDP 40        // padded LDS row stride (elems) for a 32-k chunk

typedef __attribute__((ext_vector_type(8))) short s8v;   // 8 bf16 (4 VGPRs)
typedef __attribute__((ext_vector_type(4))) float f4v;   // 4 fp32 acc

__device__ __forceinline__ float lrelu(float v){ return v > 0.f ? v : SLOPE*v; }

__device__ __forceinline__ unsigned short f2bf(float f){
  unsigned u = __float_as_uint(f);
  u += 0x7FFF + ((u>>16)&1);          // round-to-nearest-even
  return (unsigned short)(u>>16);
}
__device__ __forceinline__ float bf2f(unsigned short b){
  return __uint_as_float(((unsigned)b)<<16);
}

// ---------- block reductions (256-thread blocks = 4 waves) ----------
__device__ __forceinline__ float blockMax4(float v, float* s4){
  #pragma unroll
  for(int o=32;o>0;o>>=1) v = fmaxf(v, __shfl_down(v, o, 64));
  int t = threadIdx.x;
  __syncthreads();
  if((t&63)==0) s4[t>>6] = v;
  __syncthreads();
  return fmaxf(fmaxf(s4[0], s4[1]), fmaxf(s4[2], s4[3]));
}
__device__ __forceinline__ float blockSum4(float v, float* s4){
  #pragma unroll
  for(int o=32;o>0;o>>=1) v += __shfl_down(v, o, 64);
  int t = threadIdx.x;
  __syncthreads();
  if((t&63)==0) s4[t>>6] = v;
  __syncthreads();
  return (s4[0]+s4[1])+(s4[2]+s4[3]);
}

// ---------- CSR build (by dst) ----------
__global__ __launch_bounds__(256) void k_count(const int* __restrict__ ei, int* __restrict__ deg){
  int e = blockIdx.x*256 + threadIdx.x;
  if(e < NE) atomicAdd(&deg[ei[NE + e]], 1);
}

__global__ __launch_bounds__(1024) void k_scan(const int* __restrict__ deg,
      int* __restrict__ offs, int* __restrict__ cursor){
  __shared__ int part[1024];
  int t = threadIdx.x;
  const int4* d4 = (const int4*)(deg + t*64);
  int4 buf[16];
  int s=0;
  #pragma unroll
  for(int i=0;i<16;i++){ buf[i]=d4[i]; s += buf[i].x+buf[i].y+buf[i].z+buf[i].w; }
  part[t]=s;
  __syncthreads();
  for(int off=1; off<1024; off<<=1){
    int v = (t>=off)? part[t-off] : 0;
    __syncthreads();
    part[t] += v;
    __syncthreads();
  }
  int run = (t==0)? 0 : part[t-1];
  #pragma unroll
  for(int i=0;i<16;i++){
    int4 d = buf[i];
    int4 o;
    o.x = run; run += d.x;
    o.y = run; run += d.y;
    o.z = run; run += d.z;
    o.w = run; run += d.w;
    ((int4*)(offs + t*64))[i] = o;
    ((int4*)(cursor + t*64))[i] = o;
  }
  if(t==1023) offs[NN] = run;
}

__global__ __launch_bounds__(256) void k_scatter(const int* __restrict__ ei,
      int* __restrict__ cursor, int* __restrict__ csr){
  int e = blockIdx.x*256 + threadIdx.x;
  if(e < NE){
    int d = ei[NE + e];
    int p = atomicAdd(&cursor[d], 1);
    csr[p] = ei[e];
  }
}

// ---------- conv0: agg[i] = max over in-edges of x[src], else 0 ----------
__global__ __launch_bounds__(256) void k_agg0(const float* __restrict__ x,
    const int* __restrict__ offs, const int* __restrict__ csr, float* __restrict__ agg0){
  int tid = blockIdx.x*256 + threadIdx.x;
  int node = tid>>4, q = tid&15;
  int e0 = offs[node], e1 = offs[node+1];
  float4 acc = make_float4(0.f,0.f,0.f,0.f);
  if(e0 < e1){
    acc = make_float4(-INFINITY,-INFINITY,-INFINITY,-INFINITY);
    const int last = e1 - 1;
    for(int e=e0; e<e1; e+=8){
      int si[8];
      #pragma unroll
      for(int u=0;u<8;u++){
        int ee = e+u; ee = ee<last? ee : last;
        si[u] = csr[ee];
      }
      float4 v[8];
      #pragma unroll
      for(int u=0;u<8;u++) v[u] = ((const float4*)x)[si[u]*16 + q];
      #pragma unroll
      for(int u=0;u<8;u++){
        acc.x=fmaxf(acc.x,v[u].x); acc.y=fmaxf(acc.y,v[u].y);
        acc.z=fmaxf(acc.z,v[u].z); acc.w=fmaxf(acc.w,v[u].w);
      }
    }
  }
  ((float4*)agg0)[node*16 + q] = acc;
}

// ---------- conv0 matmul on MFMA: cur0 = lrelu([agg0|x] @ [Wrel|Wroot]^T + b0) ----------
// fp32-equivalent via hi/mid/lo bf16 split (6 products; residual ~2^-24).
__global__ __launch_bounds__(256, 2) void k_conv0mm(
    const float* __restrict__ agg0, const float* __restrict__ x,
    const float* __restrict__ Wrel, const float* __restrict__ Wroot,
    const float* __restrict__ b0, float* __restrict__ cur,
    float* __restrict__ bnsum, float* __restrict__ bnsq){
  __shared__ unsigned short Ah[128*LDP], Am[128*LDP], Al[128*LDP];
  __shared__ unsigned short Wh[128*LDP], Wm[128*LDP], Wl[128*LDP];
  const int t = threadIdx.x;
  const int wave = t>>6, lane = t&63, lm = lane&15, quad = lane>>4;
  const int rowbase = (wave>>1)*64, colbase = (wave&1)*64;
  const int nbase = blockIdx.x*128;

  f4v acc[4][4];
  #pragma unroll
  for(int i=0;i<4;i++)
    #pragma unroll
    for(int j=0;j<4;j++) acc[i][j] = (f4v){0.f,0.f,0.f,0.f};

  #pragma unroll 1
  for(int ch=0; ch<4; ch++){
    const float* gA = (ch<2 ? agg0 : x);
    const float* gW = (ch<2 ? Wrel : Wroot);
    const int kq = (ch&1)*8;
    __syncthreads();
    #pragma unroll
    for(int i=0;i<4;i++){
      int idx = t + i*256;
      int row = idx>>3, k4 = idx&7;
      float4 va = ((const float4*)gA)[(size_t)(nbase+row)*16 + kq + k4];
      float4 vw = ((const float4*)gW)[(size_t)row*16 + kq + k4];
      unsigned long long ph=0, pm=0, pl=0, qh=0, qm=0, ql=0;
      float fa[4] = {va.x,va.y,va.z,va.w};
      float fw[4] = {vw.x,vw.y,vw.z,vw.w};
      #pragma unroll
      for(int e=0;e<4;e++){
        unsigned short h = f2bf(fa[e]);
        float r1 = fa[e]-bf2f(h);
        unsigned short m = f2bf(r1);
        unsigned short l = f2bf(r1-bf2f(m));
        ph |= (unsigned long long)h << (e*16);
        pm |= (unsigned long long)m << (e*16);
        pl |= (unsigned long long)l << (e*16);
        unsigned short h2 = f2bf(fw[e]);
        float r1w = fw[e]-bf2f(h2);
        unsigned short m2 = f2bf(r1w);
        unsigned short l2 = f2bf(r1w-bf2f(m2));
        qh |= (unsigned long long)h2 << (e*16);
        qm |= (unsigned long long)m2 << (e*16);
        ql |= (unsigned long long)l2 << (e*16);
      }
      int off = row*LDP + k4*4;
      *(unsigned long long*)&Ah[off] = ph;
      *(unsigned long long*)&Am[off] = pm;
      *(unsigned long long*)&Al[off] = pl;
      *(unsigned long long*)&Wh[off] = qh;
      *(unsigned long long*)&Wm[off] = qm;
      *(unsigned long long*)&Wl[off] = ql;
    }
    __syncthreads();
    s8v ah[4], amv[4], alv[4];
    #pragma unroll
    for(int rt=0;rt<4;rt++){
      int off = (rowbase + rt*16 + lm)*LDP + quad*8;
      ah[rt]  = *(const s8v*)&Ah[off];
      amv[rt] = *(const s8v*)&Am[off];
      alv[rt] = *(const s8v*)&Al[off];
    }
    #pragma unroll
    for(int ct=0;ct<4;ct++){
      int off = (colbase + ct*16 + lm)*LDP + quad*8;
      s8v bh = *(const s8v*)&Wh[off];
      s8v bm = *(const s8v*)&Wm[off];
      s8v bl = *(const s8v*)&Wl[off];
      #pragma unroll
      for(int rt=0;rt<4;rt++){
        acc[rt][ct] = __builtin_amdgcn_mfma_f32_16x16x32_bf16(ah[rt],  bh, acc[rt][ct], 0,0,0);
        acc[rt][ct] = __builtin_amdgcn_mfma_f32_16x16x32_bf16(ah[rt],  bm, acc[rt][ct], 0,0,0);
        acc[rt][ct] = __builtin_amdgcn_mfma_f32_16x16x32_bf16(amv[rt], bh, acc[rt][ct], 0,0,0);
        acc[rt][ct] = __builtin_amdgcn_mfma_f32_16x16x32_bf16(ah[rt],  bl, acc[rt][ct], 0,0,0);
        acc[rt][ct] = __builtin_amdgcn_mfma_f32_16x16x32_bf16(alv[rt], bh, acc[rt][ct], 0,0,0);
        acc[rt][ct] = __builtin_amdgcn_mfma_f32_16x16x32_bf16(amv[rt], bm, acc[rt][ct], 0,0,0);
      }
    }
  }

  float bj[4];
  #pragma unroll
  for(int ct=0;ct<4;ct++) bj[ct] = b0[colbase + ct*16 + lm];
  float cs[4]={0.f,0.f,0.f,0.f}, cq[4]={0.f,0.f,0.f,0.f};
  #pragma unroll
  for(int rt=0;rt<4;rt++){
    #pragma unroll
    for(int ct=0;ct<4;ct++){
      int col = colbase + ct*16 + lm;
      #pragma unroll
      for(int r=0;r<4;r++){
        int row = rowbase + rt*16 + quad*4 + r;
        float v = lrelu(acc[rt][ct][r] + bj[ct]);
        cur[(size_t)(nbase+row)*128 + col] = v;
        cs[ct]+=v; cq[ct]+=v*v;
      }
    }
  }
  #pragma unroll
  for(int o=16;o<64;o<<=1){
    #pragma unroll
    for(int ct=0;ct<4;ct++){
      cs[ct] += __shfl_xor(cs[ct], o, 64);
      cq[ct] += __shfl_xor(cq[ct], o, 64);
    }
  }
  __syncthreads();
  float* redS = (float*)Ah;
  float* redQ = (float*)Am;
  if(quad==0){
    #pragma unroll
    for(int ct=0;ct<4;ct++){
      int col = colbase + ct*16 + lm;
      redS[(wave>>1)*128 + col] = cs[ct];
      redQ[(wave>>1)*128 + col] = cq[ct];
    }
  }
  __syncthreads();
  if(t<128){
    atomicAdd(&bnsum[t], redS[t]+redS[128+t]);
    atomicAdd(&bnsq[t],  redQ[t]+redQ[128+t]);
  }
}

// ---------- one pass over cur0: scores for pool0, pool1, cls (affine fold) ----------
__global__ __launch_bounds__(256) void k_scores(const float* __restrict__ cur0,
    const float* __restrict__ bns0, const float* __restrict__ bnq0,
    const float* __restrict__ g0,
    const float* __restrict__ pw0, const float* __restrict__ pw1,
    const float* __restrict__ pwc,
    float* __restrict__ scores0, float* __restrict__ pre1, float* __restrict__ pre2){
  __shared__ __align__(16) float w[12][128];
  __shared__ float sc0s[128];
  const int t = threadIdx.x;
  if(t<128){
    float mu = bns0[t]*(1.0f/NN);
    float var = bnq0[t]*(1.0f/NN) - mu*mu;
    sc0s[t] = g0[t]*rsqrtf(var+1e-5f);
  }
  __syncthreads();
  for(int i=t;i<512;i+=256){
    int h=i>>7, j=i&127;
    float s = sc0s[j];
    w[h][j]   = pw0[i]*s;
    w[4+h][j] = pw1[i]*(0.5f*s);
    w[8+h][j] = pwc[i]*(0.25f*s);
  }
  __syncthreads();
  const int tid = blockIdx.x*256 + t;
  const int n = tid>>5, k = tid&31;
  float4 v = ((const float4*)cur0)[tid];
  float a[12];
  #pragma unroll
  for(int q=0;q<12;q++){
    float4 wv = *(const float4*)&w[q][k*4];
    a[q] = v.x*wv.x + v.y*wv.y + v.z*wv.z + v.w*wv.w;
  }
  #pragma unroll
  for(int o=16;o>0;o>>=1){
    #pragma unroll
    for(int q=0;q<12;q++) a[q] += __shfl_down(a[q], o, 32);
  }
  if(k==0){
    ((float4*)scores0)[n] = make_float4(a[0],a[1],a[2],a[3]);
    ((float4*)pre1)[n]    = make_float4(a[4],a[5],a[6],a[7]);
    ((float4*)pre2)[n]    = make_float4(a[8],a[9],a[10],a[11]);
  }
}

// ---------- pool select layer 0: wave-per-head, barrier-free ----------
__global__ __launch_bounds__(256) void k_poolselW(const float* __restrict__ scores,
    float minscore, float* __restrict__ sm4, int* __restrict__ cnt,
    int* __restrict__ wl, int* __restrict__ idxP){
  const int t = threadIdx.x, g = blockIdx.x;
  const int h = t>>6, l = t&63;
  const int n0 = g*256;
  float s[4];
  #pragma unroll
  for(int i=0;i<4;i++) s[i] = scores[(size_t)(n0 + l + i*64)*4 + h];
  float m = fmaxf(fmaxf(s[0],s[1]),fmaxf(s[2],s[3]));
  #pragma unroll
  for(int o=32;o>0;o>>=1) m = fmaxf(m, __shfl_xor(m, o, 64));
  float e[4], es=0.f;
  #pragma unroll
  for(int i=0;i<4;i++){ e[i]=expf(s[i]-m); es+=e[i]; }
  #pragma unroll
  for(int o=32;o>0;o>>=1) es += __shfl_xor(es, o, 64);
  float inv = 1.f/(es+1e-16f);
  float sm[4];
  float mx = -INFINITY;
  #pragma unroll
  for(int i=0;i<4;i++){ sm[i]=e[i]*inv; mx=fmaxf(mx,sm[i]); }
  #pragma unroll
  for(int o=32;o>0;o>>=1) mx = fmaxf(mx, __shfl_xor(mx, o, 64));
  float thr = fminf(mx - 1e-7f, minscore);
  #pragma unroll
  for(int i=0;i<4;i++){
    int n = n0 + l + i*64;
    sm4[(size_t)n*4 + h] = sm[i];
    int slot = -1;
    if(sm[i] > thr){
      int p = atomicAdd(cnt, 1);
      if(p < CAP){ slot = p; wl[p] = (h<<16) | n; }
    }
    idxP[(size_t)h*NN + n] = slot;
  }
}

// ---------- layer-0 GraphConv(max) on kept items (rows = bn0(cur0)) ----------
__global__ __launch_bounds__(256) void k_blockconv0(const float* __restrict__ cur0,
    const int* __restrict__ offs, const int* __restrict__ csr,
    const int* __restrict__ idxP, const float* __restrict__ sm4,
    const int* __restrict__ cnt, const int* __restrict__ wl,
    const float* __restrict__ Wrel, const float* __restrict__ Wroot,
    const float* __restrict__ bias,
    float* __restrict__ new1c, float* __restrict__ bnsum, float* __restrict__ bnsq,
    const float* __restrict__ bns0, const float* __restrict__ bnq0,
    const float* __restrict__ g0, const float* __restrict__ b0bn){
  __shared__ __align__(16) float aggs[8][128];
  __shared__ __align__(16) float xps[8][128];
  __shared__ __align__(16) float scv[128];
  __shared__ __align__(16) float ofv[128];
  const int t = threadIdx.x, grp = t>>5, lane = t&31;
  if(t<128){
    float mu = bns0[t]*(1.0f/NN);
    float var = bnq0[t]*(1.0f/NN) - mu*mu;
    float sv = g0[t]*rsqrtf(var+1e-5f);
    scv[t]=sv; ofv[t]=b0bn[t]-mu*sv;
  }
  __syncthreads();
  const float4 s4l = *(const float4*)&scv[lane*4];
  const float4 o4l = *(const float4*)&ofv[lane*4];
  int total = *cnt; if(total > CAP) total = CAP;
  for(int item = blockIdx.x*8 + grp; item < total; item += gridDim.x*8){
    const int wv = wl[item];
    const int h = wv>>16, n = wv & 0xFFFF;
    const size_t hn = (size_t)h*NN;
    const float smn = sm4[(size_t)n*4+h];
    const int e0 = offs[n], e1 = offs[n+1];
    float4 acc = make_float4(-INFINITY,-INFINITY,-INFINITY,-INFINITY);
    bool any = false;
    for(int e=e0;e<e1;e++){
      int s = csr[e];
      if(idxP[hn + s] >= 0){
        any = true;
        float sv = sm4[(size_t)s*4+h];
        float4 v = ((const float4*)cur0)[s*32 + lane];
        v.x = (v.x*s4l.x + o4l.x)*sv; v.y = (v.y*s4l.y + o4l.y)*sv;
        v.z = (v.z*s4l.z + o4l.z)*sv; v.w = (v.w*s4l.w + o4l.w)*sv;
        acc.x = fmaxf(acc.x, v.x); acc.y = fmaxf(acc.y, v.y);
        acc.z = fmaxf(acc.z, v.z); acc.w = fmaxf(acc.w, v.w);
      }
    }
    if(!any) acc = make_float4(0.f,0.f,0.f,0.f);
    *(float4*)&aggs[grp][lane*4] = acc;
    float4 xv = ((const float4*)cur0)[n*32 + lane];
    xv.x = (xv.x*s4l.x + o4l.x)*smn; xv.y = (xv.y*s4l.y + o4l.y)*smn;
    xv.z = (xv.z*s4l.z + o4l.z)*smn; xv.w = (xv.w*s4l.w + o4l.w)*smn;
    *(float4*)&xps[grp][lane*4] = xv;
    // half-wave group: LDS write->read program-ordered within the wave
    const float* Wr = Wrel  + (size_t)(h*32+lane)*128;
    const float* Wo = Wroot + (size_t)(h*32+lane)*128;
    float o = bias[h*32+lane];
    for(int k=0;k<32;k++){
      float4 a  = *(const float4*)&aggs[grp][k*4];
      float4 xx = *(const float4*)&xps[grp][k*4];
      float4 wr = ((const float4*)Wr)[k];
      float4 wo = ((const float4*)Wo)[k];
      o += a.x*wr.x + a.y*wr.y + a.z*wr.z + a.w*wr.w;
      o += xx.x*wo.x + xx.y*wo.y + xx.z*wo.z + xx.w*wo.w;
    }
    o = lrelu(o);
    new1c[(size_t)item*32 + lane] = o;
    atomicAdd(&bnsum[h*32+lane], o);
    atomicAdd(&bnsq[h*32+lane], o*o);
  }
}

// ---------- pool select layer 1: patch phase + wave-per-head select ----------
__global__ __launch_bounds__(256) void k_poolsel1(
    const float* __restrict__ pre1, float* __restrict__ pre2,
    const int* __restrict__ cnt0, const int* __restrict__ wl0,
    const float* __restrict__ new1c,
    const float* __restrict__ bnsA, const float* __restrict__ bnqA,
    const float* __restrict__ g1v,
    const float* __restrict__ pw1, const float* __restrict__ pwc,
    float minscore, float* __restrict__ sm4out,
    int* __restrict__ cnt1, int* __restrict__ wl1, int* __restrict__ idx1P){
  __shared__ float s1s[128];
  __shared__ __align__(16) float w1s[4][128];
  __shared__ __align__(16) float wcs[4][128];
  __shared__ float patch1[256][4];
  const int t = threadIdx.x, g = blockIdx.x;
  if(t<128){
    float mu = bnsA[t]*(1.0f/NN);
    float var = bnqA[t]*(1.0f/NN) - mu*mu;
    s1s[t] = g1v[t]*rsqrtf(var+1e-5f);
  }
  for(int i=t;i<512;i+=256){ w1s[i>>7][i&127]=pw1[i]; wcs[i>>7][i&127]=pwc[i]; }
  #pragma unroll
  for(int h=0;h<4;h++) patch1[t][h]=0.f;
  __syncthreads();
  int total0 = *cnt0; if(total0 > CAP) total0 = CAP;
  for(int i=t; i<total0; i+=256){
    int wv = wl0[i];
    int n = wv & 0xFFFF, hp = wv>>16;
    if((n>>8)==g){
      int nl = n & 255;
      float d[4]={0.f,0.f,0.f,0.f}, d2[4]={0.f,0.f,0.f,0.f};
      for(int l=0;l<32;l++){
        int j = hp*32+l;
        float base = new1c[(size_t)i*32+l] * s1s[j];
        #pragma unroll
        for(int h=0;h<4;h++){ d[h]+=base*w1s[h][j]; d2[h]+=base*wcs[h][j]; }
      }
      #pragma unroll
      for(int h=0;h<4;h++){
        atomicAdd(&patch1[nl][h], 0.25f*d[h]);
        atomicAdd(&pre2[n*4+h], 0.125f*d2[h]);
      }
    }
  }
  __syncthreads();
  const int h = t>>6, l = t&63;
  const int n0 = g*256;
  float s[4];
  #pragma unroll
  for(int i=0;i<4;i++){
    int nl = l + i*64;
    s[i] = pre1[(size_t)(n0+nl)*4 + h] + patch1[nl][h];
  }
  float m = fmaxf(fmaxf(s[0],s[1]),fmaxf(s[2],s[3]));
  #pragma unroll
  for(int o=32;o>0;o>>=1) m = fmaxf(m, __shfl_xor(m, o, 64));
  float e[4], es=0.f;
  #pragma unroll
  for(int i=0;i<4;i++){ e[i]=expf(s[i]-m); es+=e[i]; }
  #pragma unroll
  for(int o=32;o>0;o>>=1) es += __shfl_xor(es, o, 64);
  float inv = 1.f/(es+1e-16f);
  float sm[4];
  float mx = -INFINITY;
  #pragma unroll
  for(int i=0;i<4;i++){ sm[i]=e[i]*inv; mx=fmaxf(mx,sm[i]); }
  #pragma unroll
  for(int o=32;o>0;o>>=1) mx = fmaxf(mx, __shfl_xor(mx, o, 64));
  float thr = fminf(mx - 1e-7f, minscore);
  #pragma unroll
  for(int i=0;i<4;i++){
    int n = n0 + l + i*64;
    sm4out[(size_t)n*4 + h] = sm[i];
    int slot = -1;
    if(sm[i] > thr){
      int p = atomicAdd(cnt1, 1);
      if(p < CAP){ slot = p; wl1[p] = (h<<16) | n; }
    }
    idx1P[(size_t)h*NN + n] = slot;
  }
}

// ---------- layer-1 GraphConv(max): rows reconstructed from cur0 + new1c ----------
__global__ __launch_bounds__(256) void k_blockconv1(const float* __restrict__ cur0,
    const int* __restrict__ offs, const int* __restrict__ csr,
    const int* __restrict__ idx0P, const float* __restrict__ new1c,
    const int* __restrict__ idx1P, const float* __restrict__ sm41,
    const int* __restrict__ cnt1, const int* __restrict__ wl1,
    const float* __restrict__ Wrel, const float* __restrict__ Wroot,
    const float* __restrict__ bias,
    float* __restrict__ new2c, float* __restrict__ bnsum, float* __restrict__ bnsq,
    const float* __restrict__ bns0, const float* __restrict__ bnq0,
    const float* __restrict__ g0, const float* __restrict__ b0bn,
    const float* __restrict__ bnsA, const float* __restrict__ bnqA,
    const float* __restrict__ g1v, const float* __restrict__ b1v){
  __shared__ __align__(16) float aggs[8][128];
  __shared__ __align__(16) float xps[8][128];
  __shared__ __align__(16) float sc0s[128], of0s[128], s1s[128], o1s[128];
  const int t = threadIdx.x, grp = t>>5, lane = t&31;
  if(t<128){
    float mu = bns0[t]*(1.0f/NN);
    float var = bnq0[t]*(1.0f/NN) - mu*mu;
    float sv = g0[t]*rsqrtf(var+1e-5f);
    sc0s[t]=sv; of0s[t]=b0bn[t]-mu*sv;
    float mu1 = bnsA[t]*(1.0f/NN);
    float var1 = bnqA[t]*(1.0f/NN) - mu1*mu1;
    float s1 = g1v[t]*rsqrtf(var1+1e-5f);
    s1s[t]=s1; o1s[t]=b1v[t]-mu1*s1;
  }
  __syncthreads();
  const float4 s0l = *(const float4*)&sc0s[lane*4];
  const float4 o0l = *(const float4*)&of0s[lane*4];
  const float4 s1l = *(const float4*)&s1s[lane*4];
  const float4 o1l = *(const float4*)&o1s[lane*4];
  const int hb = lane>>3;
  const size_t hbn = (size_t)hb*NN;
  int total = *cnt1; if(total > CAP) total = CAP;
  for(int item = blockIdx.x*8 + grp; item < total; item += gridDim.x*8){
    const int wv = wl1[item];
    const int h = wv>>16, n = wv & 0xFFFF;
    const size_t hn = (size_t)h*NN;
    const float smn = sm41[(size_t)n*4+h];
    const int e0 = offs[n], e1 = offs[n+1];
    float4 acc = make_float4(-INFINITY,-INFINITY,-INFINITY,-INFINITY);
    bool any = false;
    for(int e=e0;e<e1;e++){
      int s = csr[e];
      if(idx1P[hn + s] >= 0){
        any = true;
        float sv = sm41[(size_t)s*4+h];
        float4 c0 = ((const float4*)cur0)[s*32 + lane];
        float4 v;
        v.x = 0.5f*(s0l.x*c0.x+o0l.x) + 0.25f*o1l.x;
        v.y = 0.5f*(s0l.y*c0.y+o0l.y) + 0.25f*o1l.y;
        v.z = 0.5f*(s0l.z*c0.z+o0l.z) + 0.25f*o1l.z;
        v.w = 0.5f*(s0l.w*c0.w+o0l.w) + 0.25f*o1l.w;
        int i0 = idx0P[hbn + s];
        if(i0 >= 0){
          float4 nv = ((const float4*)(new1c + (size_t)i0*32))[lane&7];
          v.x += 0.25f*s1l.x*nv.x; v.y += 0.25f*s1l.y*nv.y;
          v.z += 0.25f*s1l.z*nv.z; v.w += 0.25f*s1l.w*nv.w;
        }
        v.x*=sv; v.y*=sv; v.z*=sv; v.w*=sv;
        acc.x = fmaxf(acc.x, v.x); acc.y = fmaxf(acc.y, v.y);
        acc.z = fmaxf(acc.z, v.z); acc.w = fmaxf(acc.w, v.w);
      }
    }
    if(!any) acc = make_float4(0.f,0.f,0.f,0.f);
    *(float4*)&aggs[grp][lane*4] = acc;
    {
      float4 c0 = ((const float4*)cur0)[n*32 + lane];
      float4 v;
      v.x = 0.5f*(s0l.x*c0.x+o0l.x) + 0.25f*o1l.x;
      v.y = 0.5f*(s0l.y*c0.y+o0l.y) + 0.25f*o1l.y;
      v.z = 0.5f*(s0l.z*c0.z+o0l.z) + 0.25f*o1l.z;
      v.w = 0.5f*(s0l.w*c0.w+o0l.w) + 0.25f*o1l.w;
      int i0 = idx0P[hbn + n];
      if(i0 >= 0){
        float4 nv = ((const float4*)(new1c + (size_t)i0*32))[lane&7];
        v.x += 0.25f*s1l.x*nv.x; v.y += 0.25f*s1l.y*nv.y;
        v.z += 0.25f*s1l.z*nv.z; v.w += 0.25f*s1l.w*nv.w;
      }
      v.x*=smn; v.y*=smn; v.z*=smn; v.w*=smn;
      *(float4*)&xps[grp][lane*4] = v;
    }
    const float* Wr = Wrel  + (size_t)(h*32+lane)*128;
    const float* Wo = Wroot + (size_t)(h*32+lane)*128;
    float o = bias[h*32+lane];
    for(int k=0;k<32;k++){
      float4 a  = *(const float4*)&aggs[grp][k*4];
      float4 xx = *(const float4*)&xps[grp][k*4];
      float4 wr = ((const float4*)Wr)[k];
      float4 wo = ((const float4*)Wo)[k];
      o += a.x*wr.x + a.y*wr.y + a.z*wr.z + a.w*wr.w;
      o += xx.x*wo.x + xx.y*wo.y + xx.z*wo.z + xx.w*wo.w;
    }
    o = lrelu(o);
    new2c[(size_t)item*32 + lane] = o;
    atomicAdd(&bnsum[h*32+lane], o);
    atomicAdd(&bnsq[h*32+lane], o*o);
  }
}

// ---------- cls: block per (graph,class); fused last-block log_softmax (r12 form) ----------
__global__ __launch_bounds__(256) void k_cls2(const float* __restrict__ cur0,
    const int* __restrict__ idx0P, const float* __restrict__ new1c,
    const int* __restrict__ idx1P, const float* __restrict__ new2c,
    const float* __restrict__ pre2, const int* __restrict__ cnt1,
    const int* __restrict__ wl1, const float* __restrict__ pwc,
    const float* __restrict__ bns0, const float* __restrict__ bnq0,
    const float* __restrict__ g0, const float* __restrict__ b0bn,
    const float* __restrict__ bnsA, const float* __restrict__ bnqA,
    const float* __restrict__ g1v, const float* __restrict__ b1v,
    const float* __restrict__ bnsB, const float* __restrict__ bnqB,
    const float* __restrict__ g2v, const float* __restrict__ b2v,
    const float* __restrict__ gW1, const float* __restrict__ gb1,
    const float* __restrict__ gW2, const float* __restrict__ gb2,
    const float* __restrict__ fW1, const float* __restrict__ fb1,
    const float* __restrict__ fW2, const float* __restrict__ fb2,
    float* __restrict__ yws, int* __restrict__ gcnt, float* __restrict__ out){
  __shared__ float red[4];
  __shared__ float sc0s[128], of0s[128], s1s[128], o1s[128], s2s[128], o2s[128];
  __shared__ float wc[128];
  __shared__ float patch[256];
  __shared__ int keptL[256];
  __shared__ float keptS[256];
  __shared__ float gateL[256];
  __shared__ __align__(16) float xk[128];
  __shared__ __align__(16) float pooled[128];
  __shared__ int nkept;
  const int t = threadIdx.x;
  const int g = blockIdx.x >> 2, c = blockIdx.x & 3;
  if(t<128){
    float mu = bns0[t]*(1.0f/NN);
    float var = bnq0[t]*(1.0f/NN) - mu*mu;
    float sv = g0[t]*rsqrtf(var+1e-5f);
    sc0s[t]=sv; of0s[t]=b0bn[t]-mu*sv;
    float mu1 = bnsA[t]*(1.0f/NN);
    float var1 = bnqA[t]*(1.0f/NN) - mu1*mu1;
    float s1 = g1v[t]*rsqrtf(var1+1e-5f);
    s1s[t]=s1; o1s[t]=b1v[t]-mu1*s1;
    float mu2 = bnsB[t]*(1.0f/NN);
    float var2 = bnqB[t]*(1.0f/NN) - mu2*mu2;
    float s2 = g2v[t]*rsqrtf(var2+1e-5f);
    s2s[t]=s2; o2s[t]=b2v[t]-mu2*s2;
    wc[t] = pwc[c*128+t];
  }
  patch[t]=0.f;
  __syncthreads();
  int total1 = *cnt1; if(total1 > CAP) total1 = CAP;
  for(int i=t; i<total1; i+=256){
    int wv = wl1[i];
    int n = wv & 0xFFFF, hp = wv>>16;
    if((n>>8)==g){
      float d=0.f;
      for(int l=0;l<32;l++){
        int j = hp*32+l;
        d += new2c[(size_t)i*32+l]*s2s[j]*wc[j];
      }
      atomicAdd(&patch[n&255], 0.25f*d);
    }
  }
  __syncthreads();
  const int n = g*256 + t;
  float sc = pre2[n*4 + c] + patch[t];
  float m = blockMax4(sc, red);
  float e = expf(sc-m);
  float ssum = blockSum4(e, red);
  float sm = e/(ssum+1e-16f);
  float smax = blockMax4(sm, red);
  float thr = fminf(smax - 1e-7f, 0.8f);
  if(t==0) nkept = 0;
  __syncthreads();
  if(sm > thr){
    int p = atomicAdd(&nkept,1);
    keptL[p]=t; keptS[p]=sm;
  }
  __syncthreads();
  const int K = nkept;
  for(int k=0;k<K;k++){
    int ln = keptL[k]; float sv = keptS[k];
    int nn = g*256 + ln;
    if(t<32){
      float4 c0 = ((const float4*)cur0)[nn*32 + t];
      float4 s0l = *(const float4*)&sc0s[t*4];
      float4 o0l = *(const float4*)&of0s[t*4];
      float4 s1l = *(const float4*)&s1s[t*4];
      float4 o1l = *(const float4*)&o1s[t*4];
      float4 s2l = *(const float4*)&s2s[t*4];
      float4 o2l = *(const float4*)&o2s[t*4];
      int hb = t>>3;
      float4 v1;
      v1.x = 0.5f*(s0l.x*c0.x+o0l.x) + 0.25f*o1l.x;
      v1.y = 0.5f*(s0l.y*c0.y+o0l.y) + 0.25f*o1l.y;
      v1.z = 0.5f*(s0l.z*c0.z+o0l.z) + 0.25f*o1l.z;
      v1.w = 0.5f*(s0l.w*c0.w+o0l.w) + 0.25f*o1l.w;
      int i0 = idx0P[(size_t)hb*NN + nn];
      if(i0 >= 0){
        float4 nv = ((const float4*)(new1c + (size_t)i0*32))[t&7];
        v1.x += 0.25f*s1l.x*nv.x; v1.y += 0.25f*s1l.y*nv.y;
        v1.z += 0.25f*s1l.z*nv.z; v1.w += 0.25f*s1l.w*nv.w;
      }
      float4 v2;
      v2.x = 0.5f*v1.x + 0.25f*o2l.x;
      v2.y = 0.5f*v1.y + 0.25f*o2l.y;
      v2.z = 0.5f*v1.z + 0.25f*o2l.z;
      v2.w = 0.5f*v1.w + 0.25f*o2l.w;
      int i1 = idx1P[(size_t)hb*NN + nn];
      if(i1 >= 0){
        float4 nv = ((const float4*)(new2c + (size_t)i1*32))[t&7];
        v2.x += 0.25f*s2l.x*nv.x; v2.y += 0.25f*s2l.y*nv.y;
        v2.z += 0.25f*s2l.z*nv.z; v2.w += 0.25f*s2l.w*nv.w;
      }
      v2.x*=sv; v2.y*=sv; v2.z*=sv; v2.w*=sv;
      *(float4*)&xk[t*4] = v2;
    }
    __syncthreads();
    float part = 0.f;
    if(t<128){
      const float* W = gW1 + (size_t)c*16384 + (size_t)t*128;
      float a = gb1[c*128+t];
      for(int f=0;f<32;f++){
        float4 xv = *(const float4*)&xk[f*4];
        float4 wv = ((const float4*)W)[f];
        a += xv.x*wv.x + xv.y*wv.y + xv.z*wv.z + xv.w*wv.w;
      }
      part = lrelu(a) * gW2[c*128+t];
    }
    float gs = blockSum4(part, red);
    if(t==0) gateL[k] = gs + gb2[c];
    __syncthreads();
  }
  float gv = (t<K)? gateL[t] : -INFINITY;
  float gm = blockMax4(gv, red);
  float ge = (t<K)? expf(gv-gm) : 0.f;
  float gsum = blockSum4(ge, red);
  if(t<K) gateL[t] = ge/(gsum+1e-16f);
  __syncthreads();
  if(t<128){
    int hb = t>>5, l = t&31;
    float acc = 0.f;
    for(int k=0;k<K;k++){
      int nn = g*256 + keptL[k];
      float c0 = cur0[(size_t)nn*128 + t];
      float v1 = 0.5f*(sc0s[t]*c0 + of0s[t]) + 0.25f*o1s[t];
      int i0 = idx0P[(size_t)hb*NN + nn];
      if(i0 >= 0) v1 += 0.25f*s1s[t]*new1c[(size_t)i0*32 + l];
      float v2 = 0.5f*v1 + 0.25f*o2s[t];
      int i1 = idx1P[(size_t)hb*NN + nn];
      if(i1 >= 0) v2 += 0.25f*s2s[t]*new2c[(size_t)i1*32 + l];
      acc += gateL[k]*keptS[k]*v2;
    }
    pooled[t]=acc;
  }
  __syncthreads();
  float part2=0.f;
  if(t<128){
    const float* F = fW1 + (size_t)c*16384 + (size_t)t*128;
    float a = fb1[c*128+t];
    for(int f=0;f<32;f++){
      float4 xv = *(const float4*)&pooled[f*4];
      float4 wv = ((const float4*)F)[f];
      a += xv.x*wv.x + xv.y*wv.y + xv.z*wv.z + xv.w*wv.w;
    }
    part2 = lrelu(a) * fW2[c*128+t];
  }
  float ysum = blockSum4(part2, red);
  if(t==0){
    yws[g*4+c] = ysum + fb2[c];
    __threadfence();
    int old = atomicAdd(&gcnt[g], 1);
    if(old == 3){
      __threadfence();
      volatile float* yv = yws + g*4;
      float y0=yv[0], y1=yv[1], y2=yv[2], y3=yv[3];
      float mm = fmaxf(fmaxf(y0,y1), fmaxf(y2,y3));
      float ll = logf(expf(y0-mm)+expf(y1-mm)+expf(y2-mm)+expf(y3-mm));
      out[g*4+0]=y0-mm-ll; out[g*4+1]=y1-mm-ll;
      out[g*4+2]=y2-mm-ll; out[g*4+3]=y3-mm-ll;
    }
  }
}

extern "C" void kernel_launch(void* const* d_in, const int* in_sizes, int n_in,
                              void* d_out, int out_size, void* d_ws, size_t ws_size,
                              hipStream_t stream){
  (void)in_sizes; (void)n_in; (void)out_size; (void)ws_size;
  const float* x     = (const float*)d_in[0];
  const int*   ei    = (const int*)d_in[1];
  const float* Wrel0 = (const float*)d_in[3];
  const float* Wroot0= (const float*)d_in[4];
  const float* b0    = (const float*)d_in[5];
  const float* bn0g  = (const float*)d_in[6];
  const float* bn0b  = (const float*)d_in[7];
  const float* bpw   = (const float*)d_in[8];
  const float* bWrel = (const float*)d_in[9];
  const float* bWroot= (const float*)d_in[10];
  const float* bbv   = (const float*)d_in[11];
  const float* bbng  = (const float*)d_in[12];
  const float* bbnb  = (const float*)d_in[13];
  const float* cpw   = (const float*)d_in[14];
  const float* gW1   = (const float*)d_in[15];
  const float* gb1   = (const float*)d_in[16];
  const float* gW2   = (const float*)d_in[17];
  const float* gb2   = (const float*)d_in[18];
  const float* fW1   = (const float*)d_in[19];
  const float* fb1   = (const float*)d_in[20];
  const float* fW2   = (const float*)d_in[21];
  const float* fb2   = (const float*)d_in[22];

  char* ws = (char*)d_ws;
  float* cur0  = (float*)(ws + 0);                  // 33.55 MB
  float* new1c = (float*)(ws + 33554432ull);        // 16.78 MB (CAP*32 floats)
  float* new2c = (float*)(ws + 50331648ull);        // 16.78 MB (aliases agg0)
  float* agg0  = new2c;                             // dead before new2c written
  int*   csr   = (int*)(ws + 67108864ull);          // 2 MB
  float* scores0=(float*)(ws + 69206016ull);        // 1 MB (sm4_0 aliases)
  float* sm40  = scores0;
  float* pre1  = (float*)(ws + 70254592ull);        // 1 MB (sm4_1 aliases)
  float* sm41  = pre1;
  float* pre2  = (float*)(ws + 71303168ull);        // 1 MB
  int*   wl0   = (int*)(ws + 72351744ull);          // 512 KB
  int*   wl1   = (int*)(ws + 72876032ull);          // 512 KB
  int*   offs  = (int*)(ws + 73400320ull);          // 256 KB + 4
  int*   cursor= (int*)(ws + 73666560ull);          // 256 KB
  int*   idx0P = (int*)(ws + 73928704ull);          // 1 MB (4 planes, always written)
  int*   idx1P = (int*)(ws + 74977280ull);          // 1 MB
  char*  Z     = ws + 76025856ull;                  // zero-init region
  int*   deg   = (int*)Z;                           // 256 KB
  float* bnsum0= (float*)(Z + 262144);
  float* bnsq0 = (float*)(Z + 262656);
  float* bnA   = (float*)(Z + 263168);
  float* bqA   = (float*)(Z + 263680);
  float* bnB   = (float*)(Z + 264192);
  float* bqB   = (float*)(Z + 264704);
  int*   cnt0  = (int*)(Z + 265216);
  int*   cnt1  = (int*)(Z + 265220);
  float* yws   = (float*)(Z + 266240);              // 4 KB
  int*   gcnt  = (int*)(Z + 270336);                // 1 KB

  hipMemsetAsync(Z, 0, 271360, stream);

  // CSR by dst
  k_count  <<<2048,256,0,stream>>>(ei, deg);
  k_scan   <<<1,1024,0,stream>>>(deg, offs, cursor);
  k_scatter<<<2048,256,0,stream>>>(ei, cursor, csr);

  // conv0 -> lrelu (+ fused bn0 stats; MFMA hi/mid/lo bf16 split)
  k_agg0    <<<4096,256,0,stream>>>(x, offs, csr, agg0);
  k_conv0mm <<<512,256,0,stream>>>(agg0, x, Wrel0, Wroot0, b0, cur0, bnsum0, bnsq0);

  // single pass: scores for pool0 + pre-scores for pool1/cls
  k_scores<<<8192,256,0,stream>>>(cur0, bnsum0, bnsq0, bn0g,
                                  bpw, bpw + 512, cpw, scores0, pre1, pre2);

  // pool layer 0 select (wave-per-head, barrier-free)
  k_poolselW<<<256,256,0,stream>>>(scores0, 0.7f, sm40, cnt0, wl0, idx0P);

  // layer-0 conv on kept items
  k_blockconv0<<<256,256,0,stream>>>(cur0, offs, csr, idx0P, sm40, cnt0, wl0,
                                     bWrel, bWroot, bbv, new1c, bnA, bqA,
                                     bnsum0, bnsq0, bn0g, bn0b);

  // pool layer 1 select (patches pre1 with layer-1 corr, pre2 partially)
  k_poolsel1<<<256,256,0,stream>>>(pre1, pre2, cnt0, wl0, new1c,
                                   bnA, bqA, bbng,
                                   bpw + 512, cpw,
                                   0.7f, sm41, cnt1, wl1, idx1P);

  // layer-1 conv on kept items (rows reconstructed)
  k_blockconv1<<<256,256,0,stream>>>(cur0, offs, csr, idx0P, new1c,
                                     idx1P, sm41, cnt1, wl1,
                                     bWrel + 16384, bWroot + 16384, bbv + 128,
                                     new2c, bnB, bqB,
                                     bnsum0, bnsq0, bn0g, bn0b,
                                     bnA, bqA, bbng, bbnb);

  // classification heads + fused per-graph log_softmax (last-block pattern)
  k_cls2<<<1024,256,0,stream>>>(cur0, idx0P, new1c, idx1P, new2c,
                                pre2, cnt1, wl1, cpw,
                                bnsum0, bnsq0, bn0g, bn0b,
                                bnA, bqA, bbng, bbnb,
                                bnB, bqB, bbng + 128, bbnb + 128,
                                gW1, gb1, gW2, gb2, fW1, fb1, fW2, fb2,
                                yws, gcnt, (float*)d_out);
}

// Round 15
// 364.345 us; speedup vs baseline: 1.1217x; 1.0191x over previous
//
#include <hip/hip_runtime.h>
#include <math.h>

#define NN 65536      // nodes
#define NE 524288     // edges
#define NG 256        // graphs (256 contiguous nodes each)
#define SLOPE 0.01f
#define CAP 131072    // worklist capacity per layer (typ. ~1k items)
#define LDP 40        // padded LDS row stride (elems) for a 32-k chunk

typedef __attribute__((ext_vector_type(8))) short s8v;   // 8 bf16 (4 VGPRs)
typedef __attribute__((ext_vector_type(4))) float f4v;   // 4 fp32 acc

__device__ __forceinline__ float lrelu(float v){ return v > 0.f ? v : SLOPE*v; }

__device__ __forceinline__ unsigned short f2bf(float f){
  unsigned u = __float_as_uint(f);
  u += 0x7FFF + ((u>>16)&1);          // round-to-nearest-even
  return (unsigned short)(u>>16);
}
__device__ __forceinline__ float bf2f(unsigned short b){
  return __uint_as_float(((unsigned)b)<<16);
}

// ---------- block reductions (256-thread blocks = 4 waves) ----------
__device__ __forceinline__ float blockMax4(float v, float* s4){
  #pragma unroll
  for(int o=32;o>0;o>>=1) v = fmaxf(v, __shfl_down(v, o, 64));
  int t = threadIdx.x;
  __syncthreads();
  if((t&63)==0) s4[t>>6] = v;
  __syncthreads();
  return fmaxf(fmaxf(s4[0], s4[1]), fmaxf(s4[2], s4[3]));
}
__device__ __forceinline__ float blockSum4(float v, float* s4){
  #pragma unroll
  for(int o=32;o>0;o>>=1) v += __shfl_down(v, o, 64);
  int t = threadIdx.x;
  __syncthreads();
  if((t&63)==0) s4[t>>6] = v;
  __syncthreads();
  return (s4[0]+s4[1])+(s4[2]+s4[3]);
}

// ---------- CSR build (by dst) ----------
__global__ __launch_bounds__(256) void k_count(const int* __restrict__ ei, int* __restrict__ deg){
  int e = blockIdx.x*256 + threadIdx.x;
  if(e < NE) atomicAdd(&deg[ei[NE + e]], 1);
}

__global__ __launch_bounds__(1024) void k_scan(const int* __restrict__ deg,
      int* __restrict__ offs, int* __restrict__ cursor){
  __shared__ int part[1024];
  int t = threadIdx.x;
  const int4* d4 = (const int4*)(deg + t*64);
  int4 buf[16];
  int s=0;
  #pragma unroll
  for(int i=0;i<16;i++){ buf[i]=d4[i]; s += buf[i].x+buf[i].y+buf[i].z+buf[i].w; }
  part[t]=s;
  __syncthreads();
  for(int off=1; off<1024; off<<=1){
    int v = (t>=off)? part[t-off] : 0;
    __syncthreads();
    part[t] += v;
    __syncthreads();
  }
  int run = (t==0)? 0 : part[t-1];
  #pragma unroll
  for(int i=0;i<16;i++){
    int4 d = buf[i];
    int4 o;
    o.x = run; run += d.x;
    o.y = run; run += d.y;
    o.z = run; run += d.z;
    o.w = run; run += d.w;
    ((int4*)(offs + t*64))[i] = o;
    ((int4*)(cursor + t*64))[i] = o;
  }
  if(t==1023) offs[NN] = run;
}

__global__ __launch_bounds__(256) void k_scatter(const int* __restrict__ ei,
      int* __restrict__ cursor, int* __restrict__ csr){
  int e = blockIdx.x*256 + threadIdx.x;
  if(e < NE){
    int d = ei[NE + e];
    int p = atomicAdd(&cursor[d], 1);
    csr[p] = ei[e];
  }
}

// ---------- conv0: agg[i] = max over in-edges of x[src], else 0 ----------
__global__ __launch_bounds__(256) void k_agg0(const float* __restrict__ x,
    const int* __restrict__ offs, const int* __restrict__ csr, float* __restrict__ agg0){
  int tid = blockIdx.x*256 + threadIdx.x;
  int node = tid>>4, q = tid&15;
  int e0 = offs[node], e1 = offs[node+1];
  float4 acc = make_float4(0.f,0.f,0.f,0.f);
  if(e0 < e1){
    acc = make_float4(-INFINITY,-INFINITY,-INFINITY,-INFINITY);
    const int last = e1 - 1;
    for(int e=e0; e<e1; e+=8){
      int si[8];
      #pragma unroll
      for(int u=0;u<8;u++){
        int ee = e+u; ee = ee<last? ee : last;
        si[u] = csr[ee];
      }
      float4 v[8];
      #pragma unroll
      for(int u=0;u<8;u++) v[u] = ((const float4*)x)[si[u]*16 + q];
      #pragma unroll
      for(int u=0;u<8;u++){
        acc.x=fmaxf(acc.x,v[u].x); acc.y=fmaxf(acc.y,v[u].y);
        acc.z=fmaxf(acc.z,v[u].z); acc.w=fmaxf(acc.w,v[u].w);
      }
    }
  }
  ((float4*)agg0)[node*16 + q] = acc;
}

// ---------- precompute W bf16 hi/mid/lo planes (r15: hoisted out of conv0mm;
// 512 blocks were each redundantly converting the same 64 KB) ----------
// plane layout: wspl[plane*16384 + ch*4096 + row*32 + k], ch=0..3
// (ch<2 -> Wrel, else Wroot; feature = (ch&1)*32 + k)
__global__ __launch_bounds__(256) void k_wsplit(const float* __restrict__ Wrel,
    const float* __restrict__ Wroot, unsigned short* __restrict__ wspl){
  int idx = blockIdx.x*256 + threadIdx.x;     // 64 blocks -> 16384
  int ch = idx>>12, row=(idx>>5)&127, k=idx&31;
  const float* src = (ch<2)? Wrel : Wroot;
  float f = src[row*64 + (ch&1)*32 + k];
  unsigned short h = f2bf(f);
  float r1 = f - bf2f(h);
  unsigned short m = f2bf(r1);
  unsigned short l = f2bf(r1 - bf2f(m));
  wspl[idx] = h;
  wspl[16384 + idx] = m;
  wspl[32768 + idx] = l;
}

// ---------- conv0 matmul on MFMA: cur0 = lrelu([agg0|x] @ [Wrel|Wroot]^T + b0) ----------
// fp32-equivalent via hi/mid/lo bf16 split (6 products; residual ~2^-24).
// r15: W planes pre-split (k_wsplit); only A converted in-kernel.
__global__ __launch_bounds__(256, 2) void k_conv0mm(
    const float* __restrict__ agg0, const float* __restrict__ x,
    const unsigned short* __restrict__ wspl,
    const float* __restrict__ b0, float* __restrict__ cur,
    float* __restrict__ bnsum, float* __restrict__ bnsq){
  __shared__ unsigned short Ah[128*LDP], Am[128*LDP], Al[128*LDP];
  __shared__ unsigned short Wh[128*LDP], Wm[128*LDP], Wl[128*LDP];
  const int t = threadIdx.x;
  const int wave = t>>6, lane = t&63, lm = lane&15, quad = lane>>4;
  const int rowbase = (wave>>1)*64, colbase = (wave&1)*64;
  const int nbase = blockIdx.x*128;

  f4v acc[4][4];
  #pragma unroll
  for(int i=0;i<4;i++)
    #pragma unroll
    for(int j=0;j<4;j++) acc[i][j] = (f4v){0.f,0.f,0.f,0.f};

  #pragma unroll 1
  for(int ch=0; ch<4; ch++){
    const float* gA = (ch<2 ? agg0 : x);
    const int kq = (ch&1)*8;
    __syncthreads();
    #pragma unroll
    for(int i=0;i<4;i++){
      int idx = t + i*256;
      int row = idx>>3, k4 = idx&7;
      float4 va = ((const float4*)gA)[(size_t)(nbase+row)*16 + kq + k4];
      int woff = ch*4096 + row*32 + k4*4;
      unsigned long long qh = *(const unsigned long long*)&wspl[woff];
      unsigned long long qm = *(const unsigned long long*)&wspl[16384 + woff];
      unsigned long long ql = *(const unsigned long long*)&wspl[32768 + woff];
      unsigned long long ph=0, pm=0, pl=0;
      float fa[4] = {va.x,va.y,va.z,va.w};
      #pragma unroll
      for(int e=0;e<4;e++){
        unsigned short h = f2bf(fa[e]);
        float r1 = fa[e]-bf2f(h);
        unsigned short m = f2bf(r1);
        unsigned short l = f2bf(r1-bf2f(m));
        ph |= (unsigned long long)h << (e*16);
        pm |= (unsigned long long)m << (e*16);
        pl |= (unsigned long long)l << (e*16);
      }
      int off = row*LDP + k4*4;
      *(unsigned long long*)&Ah[off] = ph;
      *(unsigned long long*)&Am[off] = pm;
      *(unsigned long long*)&Al[off] = pl;
      *(unsigned long long*)&Wh[off] = qh;
      *(unsigned long long*)&Wm[off] = qm;
      *(unsigned long long*)&Wl[off] = ql;
    }
    __syncthreads();
    s8v ah[4], amv[4], alv[4];
    #pragma unroll
    for(int rt=0;rt<4;rt++){
      int off = (rowbase + rt*16 + lm)*LDP + quad*8;
      ah[rt]  = *(const s8v*)&Ah[off];
      amv[rt] = *(const s8v*)&Am[off];
      alv[rt] = *(const s8v*)&Al[off];
    }
    #pragma unroll
    for(int ct=0;ct<4;ct++){
      int off = (colbase + ct*16 + lm)*LDP + quad*8;
      s8v bh = *(const s8v*)&Wh[off];
      s8v bm = *(const s8v*)&Wm[off];
      s8v bl = *(const s8v*)&Wl[off];
      #pragma unroll
      for(int rt=0;rt<4;rt++){
        acc[rt][ct] = __builtin_amdgcn_mfma_f32_16x16x32_bf16(ah[rt],  bh, acc[rt][ct], 0,0,0);
        acc[rt][ct] = __builtin_amdgcn_mfma_f32_16x16x32_bf16(ah[rt],  bm, acc[rt][ct], 0,0,0);
        acc[rt][ct] = __builtin_amdgcn_mfma_f32_16x16x32_bf16(amv[rt], bh, acc[rt][ct], 0,0,0);
        acc[rt][ct] = __builtin_amdgcn_mfma_f32_16x16x32_bf16(ah[rt],  bl, acc[rt][ct], 0,0,0);
        acc[rt][ct] = __builtin_amdgcn_mfma_f32_16x16x32_bf16(alv[rt], bh, acc[rt][ct], 0,0,0);
        acc[rt][ct] = __builtin_amdgcn_mfma_f32_16x16x32_bf16(amv[rt], bm, acc[rt][ct], 0,0,0);
      }
    }
  }

  float bj[4];
  #pragma unroll
  for(int ct=0;ct<4;ct++) bj[ct] = b0[colbase + ct*16 + lm];
  float cs[4]={0.f,0.f,0.f,0.f}, cq[4]={0.f,0.f,0.f,0.f};
  #pragma unroll
  for(int rt=0;rt<4;rt++){
    #pragma unroll
    for(int ct=0;ct<4;ct++){
      int col = colbase + ct*16 + lm;
      #pragma unroll
      for(int r=0;r<4;r++){
        int row = rowbase + rt*16 + quad*4 + r;
        float v = lrelu(acc[rt][ct][r] + bj[ct]);
        cur[(size_t)(nbase+row)*128 + col] = v;
        cs[ct]+=v; cq[ct]+=v*v;
      }
    }
  }
  #pragma unroll
  for(int o=16;o<64;o<<=1){
    #pragma unroll
    for(int ct=0;ct<4;ct++){
      cs[ct] += __shfl_xor(cs[ct], o, 64);
      cq[ct] += __shfl_xor(cq[ct], o, 64);
    }
  }
  __syncthreads();
  float* redS = (float*)Ah;
  float* redQ = (float*)Am;
  if(quad==0){
    #pragma unroll
    for(int ct=0;ct<4;ct++){
      int col = colbase + ct*16 + lm;
      redS[(wave>>1)*128 + col] = cs[ct];
      redQ[(wave>>1)*128 + col] = cq[ct];
    }
  }
  __syncthreads();
  if(t<128){
    atomicAdd(&bnsum[t], redS[t]+redS[128+t]);
    atomicAdd(&bnsq[t],  redQ[t]+redQ[128+t]);
  }
}

// ---------- one pass over cur0: scores for pool0, pool1, cls (affine fold) ----------
__global__ __launch_bounds__(256) void k_scores(const float* __restrict__ cur0,
    const float* __restrict__ bns0, const float* __restrict__ bnq0,
    const float* __restrict__ g0,
    const float* __restrict__ pw0, const float* __restrict__ pw1,
    const float* __restrict__ pwc,
    float* __restrict__ scores0, float* __restrict__ pre1, float* __restrict__ pre2){
  __shared__ __align__(16) float w[12][128];
  __shared__ float sc0s[128];
  const int t = threadIdx.x;
  if(t<128){
    float mu = bns0[t]*(1.0f/NN);
    float var = bnq0[t]*(1.0f/NN) - mu*mu;
    sc0s[t] = g0[t]*rsqrtf(var+1e-5f);
  }
  __syncthreads();
  for(int i=t;i<512;i+=256){
    int h=i>>7, j=i&127;
    float s = sc0s[j];
    w[h][j]   = pw0[i]*s;
    w[4+h][j] = pw1[i]*(0.5f*s);
    w[8+h][j] = pwc[i]*(0.25f*s);
  }
  __syncthreads();
  const int tid = blockIdx.x*256 + t;
  const int n = tid>>5, k = tid&31;
  float4 v = ((const float4*)cur0)[tid];
  float a[12];
  #pragma unroll
  for(int q=0;q<12;q++){
    float4 wv = *(const float4*)&w[q][k*4];
    a[q] = v.x*wv.x + v.y*wv.y + v.z*wv.z + v.w*wv.w;
  }
  #pragma unroll
  for(int o=16;o>0;o>>=1){
    #pragma unroll
    for(int q=0;q<12;q++) a[q] += __shfl_down(a[q], o, 32);
  }
  if(k==0){
    ((float4*)scores0)[n] = make_float4(a[0],a[1],a[2],a[3]);
    ((float4*)pre1)[n]    = make_float4(a[4],a[5],a[6],a[7]);
    ((float4*)pre2)[n]    = make_float4(a[8],a[9],a[10],a[11]);
  }
}

// ---------- pool select layer 0: wave-per-head, barrier-free ----------
__global__ __launch_bounds__(256) void k_poolselW(const float* __restrict__ scores,
    float minscore, float* __restrict__ sm4, int* __restrict__ cnt,
    int* __restrict__ wl, int* __restrict__ idxP){
  const int t = threadIdx.x, g = blockIdx.x;
  const int h = t>>6, l = t&63;
  const int n0 = g*256;
  float s[4];
  #pragma unroll
  for(int i=0;i<4;i++) s[i] = scores[(size_t)(n0 + l + i*64)*4 + h];
  float m = fmaxf(fmaxf(s[0],s[1]),fmaxf(s[2],s[3]));
  #pragma unroll
  for(int o=32;o>0;o>>=1) m = fmaxf(m, __shfl_xor(m, o, 64));
  float e[4], es=0.f;
  #pragma unroll
  for(int i=0;i<4;i++){ e[i]=expf(s[i]-m); es+=e[i]; }
  #pragma unroll
  for(int o=32;o>0;o>>=1) es += __shfl_xor(es, o, 64);
  float inv = 1.f/(es+1e-16f);
  float sm[4];
  float mx = -INFINITY;
  #pragma unroll
  for(int i=0;i<4;i++){ sm[i]=e[i]*inv; mx=fmaxf(mx,sm[i]); }
  #pragma unroll
  for(int o=32;o>0;o>>=1) mx = fmaxf(mx, __shfl_xor(mx, o, 64));
  float thr = fminf(mx - 1e-7f, minscore);
  #pragma unroll
  for(int i=0;i<4;i++){
    int n = n0 + l + i*64;
    sm4[(size_t)n*4 + h] = sm[i];
    int slot = -1;
    if(sm[i] > thr){
      int p = atomicAdd(cnt, 1);
      if(p < CAP){ slot = p; wl[p] = (h<<16) | n; }
    }
    idxP[(size_t)h*NN + n] = slot;
  }
}

// ---------- layer-0 GraphConv(max) on kept items (rows = bn0(cur0)) ----------
__global__ __launch_bounds__(256) void k_blockconv0(const float* __restrict__ cur0,
    const int* __restrict__ offs, const int* __restrict__ csr,
    const int* __restrict__ idxP, const float* __restrict__ sm4,
    const int* __restrict__ cnt, const int* __restrict__ wl,
    const float* __restrict__ Wrel, const float* __restrict__ Wroot,
    const float* __restrict__ bias,
    float* __restrict__ new1c, float* __restrict__ bnsum, float* __restrict__ bnsq,
    const float* __restrict__ bns0, const float* __restrict__ bnq0,
    const float* __restrict__ g0, const float* __restrict__ b0bn){
  __shared__ __align__(16) float aggs[8][128];
  __shared__ __align__(16) float xps[8][128];
  __shared__ __align__(16) float scv[128];
  __shared__ __align__(16) float ofv[128];
  const int t = threadIdx.x, grp = t>>5, lane = t&31;
  if(t<128){
    float mu = bns0[t]*(1.0f/NN);
    float var = bnq0[t]*(1.0f/NN) - mu*mu;
    float sv = g0[t]*rsqrtf(var+1e-5f);
    scv[t]=sv; ofv[t]=b0bn[t]-mu*sv;
  }
  __syncthreads();
  const float4 s4l = *(const float4*)&scv[lane*4];
  const float4 o4l = *(const float4*)&ofv[lane*4];
  int total = *cnt; if(total > CAP) total = CAP;
  for(int item = blockIdx.x*8 + grp; item < total; item += gridDim.x*8){
    const int wv = wl[item];
    const int h = wv>>16, n = wv & 0xFFFF;
    const size_t hn = (size_t)h*NN;
    const float smn = sm4[(size_t)n*4+h];
    const int e0 = offs[n], e1 = offs[n+1];
    float4 acc = make_float4(-INFINITY,-INFINITY,-INFINITY,-INFINITY);
    bool any = false;
    for(int e=e0;e<e1;e++){
      int s = csr[e];
      if(idxP[hn + s] >= 0){
        any = true;
        float sv = sm4[(size_t)s*4+h];
        float4 v = ((const float4*)cur0)[s*32 + lane];
        v.x = (v.x*s4l.x + o4l.x)*sv; v.y = (v.y*s4l.y + o4l.y)*sv;
        v.z = (v.z*s4l.z + o4l.z)*sv; v.w = (v.w*s4l.w + o4l.w)*sv;
        acc.x = fmaxf(acc.x, v.x); acc.y = fmaxf(acc.y, v.y);
        acc.z = fmaxf(acc.z, v.z); acc.w = fmaxf(acc.w, v.w);
      }
    }
    if(!any) acc = make_float4(0.f,0.f,0.f,0.f);
    *(float4*)&aggs[grp][lane*4] = acc;
    float4 xv = ((const float4*)cur0)[n*32 + lane];
    xv.x = (xv.x*s4l.x + o4l.x)*smn; xv.y = (xv.y*s4l.y + o4l.y)*smn;
    xv.z = (xv.z*s4l.z + o4l.z)*smn; xv.w = (xv.w*s4l.w + o4l.w)*smn;
    *(float4*)&xps[grp][lane*4] = xv;
    // half-wave group: LDS write->read program-ordered within the wave
    const float* Wr = Wrel  + (size_t)(h*32+lane)*128;
    const float* Wo = Wroot + (size_t)(h*32+lane)*128;
    float o = bias[h*32+lane];
    for(int k=0;k<32;k++){
      float4 a  = *(const float4*)&aggs[grp][k*4];
      float4 xx = *(const float4*)&xps[grp][k*4];
      float4 wr = ((const float4*)Wr)[k];
      float4 wo = ((const float4*)Wo)[k];
      o += a.x*wr.x + a.y*wr.y + a.z*wr.z + a.w*wr.w;
      o += xx.x*wo.x + xx.y*wo.y + xx.z*wo.z + xx.w*wo.w;
    }
    o = lrelu(o);
    new1c[(size_t)item*32 + lane] = o;
    atomicAdd(&bnsum[h*32+lane], o);
    atomicAdd(&bnsq[h*32+lane], o*o);
  }
}

// ---------- pool select layer 1: patch phase + wave-per-head select ----------
__global__ __launch_bounds__(256) void k_poolsel1(
    const float* __restrict__ pre1, float* __restrict__ pre2,
    const int* __restrict__ cnt0, const int* __restrict__ wl0,
    const float* __restrict__ new1c,
    const float* __restrict__ bnsA, const float* __restrict__ bnqA,
    const float* __restrict__ g1v,
    const float* __restrict__ pw1, const float* __restrict__ pwc,
    float minscore, float* __restrict__ sm4out,
    int* __restrict__ cnt1, int* __restrict__ wl1, int* __restrict__ idx1P){
  __shared__ float s1s[128];
  __shared__ __align__(16) float w1s[4][128];
  __shared__ __align__(16) float wcs[4][128];
  __shared__ float patch1[256][4];
  const int t = threadIdx.x, g = blockIdx.x;
  if(t<128){
    float mu = bnsA[t]*(1.0f/NN);
    float var = bnqA[t]*(1.0f/NN) - mu*mu;
    s1s[t] = g1v[t]*rsqrtf(var+1e-5f);
  }
  for(int i=t;i<512;i+=256){ w1s[i>>7][i&127]=pw1[i]; wcs[i>>7][i&127]=pwc[i]; }
  #pragma unroll
  for(int h=0;h<4;h++) patch1[t][h]=0.f;
  __syncthreads();
  int total0 = *cnt0; if(total0 > CAP) total0 = CAP;
  for(int i=t; i<total0; i+=256){
    int wv = wl0[i];
    int n = wv & 0xFFFF, hp = wv>>16;
    if((n>>8)==g){
      int nl = n & 255;
      float d[4]={0.f,0.f,0.f,0.f}, d2[4]={0.f,0.f,0.f,0.f};
      for(int l=0;l<32;l++){
        int j = hp*32+l;
        float base = new1c[(size_t)i*32+l] * s1s[j];
        #pragma unroll
        for(int h=0;h<4;h++){ d[h]+=base*w1s[h][j]; d2[h]+=base*wcs[h][j]; }
      }
      #pragma unroll
      for(int h=0;h<4;h++){
        atomicAdd(&patch1[nl][h], 0.25f*d[h]);
        atomicAdd(&pre2[n*4+h], 0.125f*d2[h]);
      }
    }
  }
  __syncthreads();
  const int h = t>>6, l = t&63;
  const int n0 = g*256;
  float s[4];
  #pragma unroll
  for(int i=0;i<4;i++){
    int nl = l + i*64;
    s[i] = pre1[(size_t)(n0+nl)*4 + h] + patch1[nl][h];
  }
  float m = fmaxf(fmaxf(s[0],s[1]),fmaxf(s[2],s[3]));
  #pragma unroll
  for(int o=32;o>0;o>>=1) m = fmaxf(m, __shfl_xor(m, o, 64));
  float e[4], es=0.f;
  #pragma unroll
  for(int i=0;i<4;i++){ e[i]=expf(s[i]-m); es+=e[i]; }
  #pragma unroll
  for(int o=32;o>0;o>>=1) es += __shfl_xor(es, o, 64);
  float inv = 1.f/(es+1e-16f);
  float sm[4];
  float mx = -INFINITY;
  #pragma unroll
  for(int i=0;i<4;i++){ sm[i]=e[i]*inv; mx=fmaxf(mx,sm[i]); }
  #pragma unroll
  for(int o=32;o>0;o>>=1) mx = fmaxf(mx, __shfl_xor(mx, o, 64));
  float thr = fminf(mx - 1e-7f, minscore);
  #pragma unroll
  for(int i=0;i<4;i++){
    int n = n0 + l + i*64;
    sm4out[(size_t)n*4 + h] = sm[i];
    int slot = -1;
    if(sm[i] > thr){
      int p = atomicAdd(cnt1, 1);
      if(p < CAP){ slot = p; wl1[p] = (h<<16) | n; }
    }
    idx1P[(size_t)h*NN + n] = slot;
  }
}

// ---------- layer-1 GraphConv(max): rows reconstructed from cur0 + new1c ----------
__global__ __launch_bounds__(256) void k_blockconv1(const float* __restrict__ cur0,
    const int* __restrict__ offs, const int* __restrict__ csr,
    const int* __restrict__ idx0P, const float* __restrict__ new1c,
    const int* __restrict__ idx1P, const float* __restrict__ sm41,
    const int* __restrict__ cnt1, const int* __restrict__ wl1,
    const float* __restrict__ Wrel, const float* __restrict__ Wroot,
    const float* __restrict__ bias,
    float* __restrict__ new2c, float* __restrict__ bnsum, float* __restrict__ bnsq,
    const float* __restrict__ bns0, const float* __restrict__ bnq0,
    const float* __restrict__ g0, const float* __restrict__ b0bn,
    const float* __restrict__ bnsA, const float* __restrict__ bnqA,
    const float* __restrict__ g1v, const float* __restrict__ b1v){
  __shared__ __align__(16) float aggs[8][128];
  __shared__ __align__(16) float xps[8][128];
  __shared__ __align__(16) float sc0s[128], of0s[128], s1s[128], o1s[128];
  const int t = threadIdx.x, grp = t>>5, lane = t&31;
  if(t<128){
    float mu = bns0[t]*(1.0f/NN);
    float var = bnq0[t]*(1.0f/NN) - mu*mu;
    float sv = g0[t]*rsqrtf(var+1e-5f);
    sc0s[t]=sv; of0s[t]=b0bn[t]-mu*sv;
    float mu1 = bnsA[t]*(1.0f/NN);
    float var1 = bnqA[t]*(1.0f/NN) - mu1*mu1;
    float s1 = g1v[t]*rsqrtf(var1+1e-5f);
    s1s[t]=s1; o1s[t]=b1v[t]-mu1*s1;
  }
  __syncthreads();
  const float4 s0l = *(const float4*)&sc0s[lane*4];
  const float4 o0l = *(const float4*)&of0s[lane*4];
  const float4 s1l = *(const float4*)&s1s[lane*4];
  const float4 o1l = *(const float4*)&o1s[lane*4];
  const int hb = lane>>3;
  const size_t hbn = (size_t)hb*NN;
  int total = *cnt1; if(total > CAP) total = CAP;
  for(int item = blockIdx.x*8 + grp; item < total; item += gridDim.x*8){
    const int wv = wl1[item];
    const int h = wv>>16, n = wv & 0xFFFF;
    const size_t hn = (size_t)h*NN;
    const float smn = sm41[(size_t)n*4+h];
    const int e0 = offs[n], e1 = offs[n+1];
    float4 acc = make_float4(-INFINITY,-INFINITY,-INFINITY,-INFINITY);
    bool any = false;
    for(int e=e0;e<e1;e++){
      int s = csr[e];
      if(idx1P[hn + s] >= 0){
        any = true;
        float sv = sm41[(size_t)s*4+h];
        float4 c0 = ((const float4*)cur0)[s*32 + lane];
        float4 v;
        v.x = 0.5f*(s0l.x*c0.x+o0l.x) + 0.25f*o1l.x;
        v.y = 0.5f*(s0l.y*c0.y+o0l.y) + 0.25f*o1l.y;
        v.z = 0.5f*(s0l.z*c0.z+o0l.z) + 0.25f*o1l.z;
        v.w = 0.5f*(s0l.w*c0.w+o0l.w) + 0.25f*o1l.w;
        int i0 = idx0P[hbn + s];
        if(i0 >= 0){
          float4 nv = ((const float4*)(new1c + (size_t)i0*32))[lane&7];
          v.x += 0.25f*s1l.x*nv.x; v.y += 0.25f*s1l.y*nv.y;
          v.z += 0.25f*s1l.z*nv.z; v.w += 0.25f*s1l.w*nv.w;
        }
        v.x*=sv; v.y*=sv; v.z*=sv; v.w*=sv;
        acc.x = fmaxf(acc.x, v.x); acc.y = fmaxf(acc.y, v.y);
        acc.z = fmaxf(acc.z, v.z); acc.w = fmaxf(acc.w, v.w);
      }
    }
    if(!any) acc = make_float4(0.f,0.f,0.f,0.f);
    *(float4*)&aggs[grp][lane*4] = acc;
    {
      float4 c0 = ((const float4*)cur0)[n*32 + lane];
      float4 v;
      v.x = 0.5f*(s0l.x*c0.x+o0l.x) + 0.25f*o1l.x;
      v.y = 0.5f*(s0l.y*c0.y+o0l.y) + 0.25f*o1l.y;
      v.z = 0.5f*(s0l.z*c0.z+o0l.z) + 0.25f*o1l.z;
      v.w = 0.5f*(s0l.w*c0.w+o0l.w) + 0.25f*o1l.w;
      int i0 = idx0P[hbn + n];
      if(i0 >= 0){
        float4 nv = ((const float4*)(new1c + (size_t)i0*32))[lane&7];
        v.x += 0.25f*s1l.x*nv.x; v.y += 0.25f*s1l.y*nv.y;
        v.z += 0.25f*s1l.z*nv.z; v.w += 0.25f*s1l.w*nv.w;
      }
      v.x*=smn; v.y*=smn; v.z*=smn; v.w*=smn;
      *(float4*)&xps[grp][lane*4] = v;
    }
    const float* Wr = Wrel  + (size_t)(h*32+lane)*128;
    const float* Wo = Wroot + (size_t)(h*32+lane)*128;
    float o = bias[h*32+lane];
    for(int k=0;k<32;k++){
      float4 a  = *(const float4*)&aggs[grp][k*4];
      float4 xx = *(const float4*)&xps[grp][k*4];
      float4 wr = ((const float4*)Wr)[k];
      float4 wo = ((const float4*)Wo)[k];
      o += a.x*wr.x + a.y*wr.y + a.z*wr.z + a.w*wr.w;
      o += xx.x*wo.x + xx.y*wo.y + xx.z*wo.z + xx.w*wo.w;
    }
    o = lrelu(o);
    new2c[(size_t)item*32 + lane] = o;
    atomicAdd(&bnsum[h*32+lane], o);
    atomicAdd(&bnsq[h*32+lane], o*o);
  }
}

// ---------- cls: block per (graph,class); K==1 gate shortcut (r15) ----------
__global__ __launch_bounds__(256) void k_cls2(const float* __restrict__ cur0,
    const int* __restrict__ idx0P, const float* __restrict__ new1c,
    const int* __restrict__ idx1P, const float* __restrict__ new2c,
    const float* __restrict__ pre2, const int* __restrict__ cnt1,
    const int* __restrict__ wl1, const float* __restrict__ pwc,
    const float* __restrict__ bns0, const float* __restrict__ bnq0,
    const float* __restrict__ g0, const float* __restrict__ b0bn,
    const float* __restrict__ bnsA, const float* __restrict__ bnqA,
    const float* __restrict__ g1v, const float* __restrict__ b1v,
    const float* __restrict__ bnsB, const float* __restrict__ bnqB,
    const float* __restrict__ g2v, const float* __restrict__ b2v,
    const float* __restrict__ gW1, const float* __restrict__ gb1,
    const float* __restrict__ gW2, const float* __restrict__ gb2,
    const float* __restrict__ fW1, const float* __restrict__ fb1,
    const float* __restrict__ fW2, const float* __restrict__ fb2,
    float* __restrict__ yws, int* __restrict__ gcnt, float* __restrict__ out){
  __shared__ float red[4];
  __shared__ float sc0s[128], of0s[128], s1s[128], o1s[128], s2s[128], o2s[128];
  __shared__ float wc[128];
  __shared__ float patch[256];
  __shared__ int keptL[256];
  __shared__ float keptS[256];
  __shared__ float gateL[256];
  __shared__ __align__(16) float xk[128];
  __shared__ __align__(16) float pooled[128];
  __shared__ int nkept;
  const int t = threadIdx.x;
  const int g = blockIdx.x >> 2, c = blockIdx.x & 3;
  if(t<128){
    float mu = bns0[t]*(1.0f/NN);
    float var = bnq0[t]*(1.0f/NN) - mu*mu;
    float sv = g0[t]*rsqrtf(var+1e-5f);
    sc0s[t]=sv; of0s[t]=b0bn[t]-mu*sv;
    float mu1 = bnsA[t]*(1.0f/NN);
    float var1 = bnqA[t]*(1.0f/NN) - mu1*mu1;
    float s1 = g1v[t]*rsqrtf(var1+1e-5f);
    s1s[t]=s1; o1s[t]=b1v[t]-mu1*s1;
    float mu2 = bnsB[t]*(1.0f/NN);
    float var2 = bnqB[t]*(1.0f/NN) - mu2*mu2;
    float s2 = g2v[t]*rsqrtf(var2+1e-5f);
    s2s[t]=s2; o2s[t]=b2v[t]-mu2*s2;
    wc[t] = pwc[c*128+t];
  }
  patch[t]=0.f;
  __syncthreads();
  int total1 = *cnt1; if(total1 > CAP) total1 = CAP;
  for(int i=t; i<total1; i+=256){
    int wv = wl1[i];
    int n = wv & 0xFFFF, hp = wv>>16;
    if((n>>8)==g){
      float d=0.f;
      for(int l=0;l<32;l++){
        int j = hp*32+l;
        d += new2c[(size_t)i*32+l]*s2s[j]*wc[j];
      }
      atomicAdd(&patch[n&255], 0.25f*d);
    }
  }
  __syncthreads();
  const int n = g*256 + t;
  float sc = pre2[n*4 + c] + patch[t];
  float m = blockMax4(sc, red);
  float e = expf(sc-m);
  float ssum = blockSum4(e, red);
  float sm = e/(ssum+1e-16f);
  float smax = blockMax4(sm, red);
  float thr = fminf(smax - 1e-7f, 0.8f);
  if(t==0) nkept = 0;
  __syncthreads();
  if(sm > thr){
    int p = atomicAdd(&nkept,1);
    keptL[p]=t; keptS[p]=sm;
  }
  __syncthreads();
  const int K = nkept;
  if(K != 1){
    // general path: per-kept gate matvec + gate softmax
    for(int k=0;k<K;k++){
      int ln = keptL[k]; float sv = keptS[k];
      int nn = g*256 + ln;
      if(t<32){
        float4 c0 = ((const float4*)cur0)[nn*32 + t];
        float4 s0l = *(const float4*)&sc0s[t*4];
        float4 o0l = *(const float4*)&of0s[t*4];
        float4 s1l = *(const float4*)&s1s[t*4];
        float4 o1l = *(const float4*)&o1s[t*4];
        float4 s2l = *(const float4*)&s2s[t*4];
        float4 o2l = *(const float4*)&o2s[t*4];
        int hb = t>>3;
        float4 v1;
        v1.x = 0.5f*(s0l.x*c0.x+o0l.x) + 0.25f*o1l.x;
        v1.y = 0.5f*(s0l.y*c0.y+o0l.y) + 0.25f*o1l.y;
        v1.z = 0.5f*(s0l.z*c0.z+o0l.z) + 0.25f*o1l.z;
        v1.w = 0.5f*(s0l.w*c0.w+o0l.w) + 0.25f*o1l.w;
        int i0 = idx0P[(size_t)hb*NN + nn];
        if(i0 >= 0){
          float4 nv = ((const float4*)(new1c + (size_t)i0*32))[t&7];
          v1.x += 0.25f*s1l.x*nv.x; v1.y += 0.25f*s1l.y*nv.y;
          v1.z += 0.25f*s1l.z*nv.z; v1.w += 0.25f*s1l.w*nv.w;
        }
        float4 v2;
        v2.x = 0.5f*v1.x + 0.25f*o2l.x;
        v2.y = 0.5f*v1.y + 0.25f*o2l.y;
        v2.z = 0.5f*v1.z + 0.25f*o2l.z;
        v2.w = 0.5f*v1.w + 0.25f*o2l.w;
        int i1 = idx1P[(size_t)hb*NN + nn];
        if(i1 >= 0){
          float4 nv = ((const float4*)(new2c + (size_t)i1*32))[t&7];
          v2.x += 0.25f*s2l.x*nv.x; v2.y += 0.25f*s2l.y*nv.y;
          v2.z += 0.25f*s2l.z*nv.z; v2.w += 0.25f*s2l.w*nv.w;
        }
        v2.x*=sv; v2.y*=sv; v2.z*=sv; v2.w*=sv;
        *(float4*)&xk[t*4] = v2;
      }
      __syncthreads();
      float part = 0.f;
      if(t<128){
        const float* W = gW1 + (size_t)c*16384 + (size_t)t*128;
        float a = gb1[c*128+t];
        for(int f=0;f<32;f++){
          float4 xv = *(const float4*)&xk[f*4];
          float4 wv = ((const float4*)W)[f];
          a += xv.x*wv.x + xv.y*wv.y + xv.z*wv.z + xv.w*wv.w;
        }
        part = lrelu(a) * gW2[c*128+t];
      }
      float gs = blockSum4(part, red);
      if(t==0) gateL[k] = gs + gb2[c];
      __syncthreads();
    }
    float gv = (t<K)? gateL[t] : -INFINITY;
    float gm = blockMax4(gv, red);
    float ge = (t<K)? expf(gv-gm) : 0.f;
    float gsum = blockSum4(ge, red);
    if(t<K) gateL[t] = ge/(gsum+1e-16f);
  } else {
    // K==1: softmax over a single gate logit is exactly 1.0 -> skip the
    // gate matvec entirely (exact, not approximate)
    if(t==0) gateL[0] = 1.0f;
  }
  __syncthreads();
  if(t<128){
    int hb = t>>5, l = t&31;
    float acc = 0.f;
    for(int k=0;k<K;k++){
      int nn = g*256 + keptL[k];
      float c0 = cur0[(size_t)nn*128 + t];
      float v1 = 0.5f*(sc0s[t]*c0 + of0s[t]) + 0.25f*o1s[t];
      int i0 = idx0P[(size_t)hb*NN + nn];
      if(i0 >= 0) v1 += 0.25f*s1s[t]*new1c[(size_t)i0*32 + l];
      float v2 = 0.5f*v1 + 0.25f*o2s[t];
      int i1 = idx1P[(size_t)hb*NN + nn];
      if(i1 >= 0) v2 += 0.25f*s2s[t]*new2c[(size_t)i1*32 + l];
      acc += gateL[k]*keptS[k]*v2;
    }
    pooled[t]=acc;
  }
  __syncthreads();
  float part2=0.f;
  if(t<128){
    const float* F = fW1 + (size_t)c*16384 + (size_t)t*128;
    float a = fb1[c*128+t];
    for(int f=0;f<32;f++){
      float4 xv = *(const float4*)&pooled[f*4];
      float4 wv = ((const float4*)F)[f];
      a += xv.x*wv.x + xv.y*wv.y + xv.z*wv.z + xv.w*wv.w;
    }
    part2 = lrelu(a) * fW2[c*128+t];
  }
  float ysum = blockSum4(part2, red);
  if(t==0){
    yws[g*4+c] = ysum + fb2[c];
    __threadfence();
    int old = atomicAdd(&gcnt[g], 1);
    if(old == 3){
      __threadfence();
      volatile float* yv = yws + g*4;
      float y0=yv[0], y1=yv[1], y2=yv[2], y3=yv[3];
      float mm = fmaxf(fmaxf(y0,y1), fmaxf(y2,y3));
      float ll = logf(expf(y0-mm)+expf(y1-mm)+expf(y2-mm)+expf(y3-mm));
      out[g*4+0]=y0-mm-ll; out[g*4+1]=y1-mm-ll;
      out[g*4+2]=y2-mm-ll; out[g*4+3]=y3-mm-ll;
    }
  }
}

extern "C" void kernel_launch(void* const* d_in, const int* in_sizes, int n_in,
                              void* d_out, int out_size, void* d_ws, size_t ws_size,
                              hipStream_t stream){
  (void)in_sizes; (void)n_in; (void)out_size; (void)ws_size;
  const float* x     = (const float*)d_in[0];
  const int*   ei    = (const int*)d_in[1];
  const float* Wrel0 = (const float*)d_in[3];
  const float* Wroot0= (const float*)d_in[4];
  const float* b0    = (const float*)d_in[5];
  const float* bn0g  = (const float*)d_in[6];
  const float* bn0b  = (const float*)d_in[7];
  const float* bpw   = (const float*)d_in[8];
  const float* bWrel = (const float*)d_in[9];
  const float* bWroot= (const float*)d_in[10];
  const float* bbv   = (const float*)d_in[11];
  const float* bbng  = (const float*)d_in[12];
  const float* bbnb  = (const float*)d_in[13];
  const float* cpw   = (const float*)d_in[14];
  const float* gW1   = (const float*)d_in[15];
  const float* gb1   = (const float*)d_in[16];
  const float* gW2   = (const float*)d_in[17];
  const float* gb2   = (const float*)d_in[18];
  const float* fW1   = (const float*)d_in[19];
  const float* fb1   = (const float*)d_in[20];
  const float* fW2   = (const float*)d_in[21];
  const float* fb2   = (const float*)d_in[22];

  char* ws = (char*)d_ws;
  float* cur0  = (float*)(ws + 0);                  // 33.55 MB
  float* new1c = (float*)(ws + 33554432ull);        // 16.78 MB (CAP*32 floats)
  float* new2c = (float*)(ws + 50331648ull);        // 16.78 MB (aliases agg0)
  float* agg0  = new2c;                             // dead before new2c written
  int*   csr   = (int*)(ws + 67108864ull);          // 2 MB
  float* scores0=(float*)(ws + 69206016ull);        // 1 MB (sm4_0 aliases)
  float* sm40  = scores0;
  float* pre1  = (float*)(ws + 70254592ull);        // 1 MB (sm4_1 aliases)
  float* sm41  = pre1;
  float* pre2  = (float*)(ws + 71303168ull);        // 1 MB
  int*   wl0   = (int*)(ws + 72351744ull);          // 512 KB
  int*   wl1   = (int*)(ws + 72876032ull);          // 512 KB
  int*   offs  = (int*)(ws + 73400320ull);          // 256 KB + 4
  int*   cursor= (int*)(ws + 73666560ull);          // 256 KB
  int*   idx0P = (int*)(ws + 73928704ull);          // 1 MB (4 planes, always written)
  int*   idx1P = (int*)(ws + 74977280ull);          // 1 MB
  char*  Z     = ws + 76025856ull;                  // zero-init region
  int*   deg   = (int*)Z;                           // 256 KB
  float* bnsum0= (float*)(Z + 262144);
  float* bnsq0 = (float*)(Z + 262656);
  float* bnA   = (float*)(Z + 263168);
  float* bqA   = (float*)(Z + 263680);
  float* bnB   = (float*)(Z + 264192);
  float* bqB   = (float*)(Z + 264704);
  int*   cnt0  = (int*)(Z + 265216);
  int*   cnt1  = (int*)(Z + 265220);
  float* yws   = (float*)(Z + 266240);              // 4 KB
  int*   gcnt  = (int*)(Z + 270336);                // 1 KB
  unsigned short* wspl = (unsigned short*)(ws + 76297216ull);  // 96 KB W planes

  hipMemsetAsync(Z, 0, 271360, stream);

  // precompute W bf16 planes (once; 512 conv0mm blocks reuse)
  k_wsplit<<<64,256,0,stream>>>(Wrel0, Wroot0, wspl);

  // CSR by dst
  k_count  <<<2048,256,0,stream>>>(ei, deg);
  k_scan   <<<1,1024,0,stream>>>(deg, offs, cursor);
  k_scatter<<<2048,256,0,stream>>>(ei, cursor, csr);

  // conv0 -> lrelu (+ fused bn0 stats; MFMA hi/mid/lo bf16 split)
  k_agg0    <<<4096,256,0,stream>>>(x, offs, csr, agg0);
  k_conv0mm <<<512,256,0,stream>>>(agg0, x, wspl, b0, cur0, bnsum0, bnsq0);

  // single pass: scores for pool0 + pre-scores for pool1/cls
  k_scores<<<8192,256,0,stream>>>(cur0, bnsum0, bnsq0, bn0g,
                                  bpw, bpw + 512, cpw, scores0, pre1, pre2);

  // pool layer 0 select (wave-per-head, barrier-free)
  k_poolselW<<<256,256,0,stream>>>(scores0, 0.7f, sm40, cnt0, wl0, idx0P);

  // layer-0 conv on kept items
  k_blockconv0<<<256,256,0,stream>>>(cur0, offs, csr, idx0P, sm40, cnt0, wl0,
                                     bWrel, bWroot, bbv, new1c, bnA, bqA,
                                     bnsum0, bnsq0, bn0g, bn0b);

  // pool layer 1 select (patches pre1 with layer-1 corr, pre2 partially)
  k_poolsel1<<<256,256,0,stream>>>(pre1, pre2, cnt0, wl0, new1c,
                                   bnA, bqA, bbng,
                                   bpw + 512, cpw,
                                   0.7f, sm41, cnt1, wl1, idx1P);

  // layer-1 conv on kept items (rows reconstructed)
  k_blockconv1<<<256,256,0,stream>>>(cur0, offs, csr, idx0P, new1c,
                                     idx1P, sm41, cnt1, wl1,
                                     bWrel + 16384, bWroot + 16384, bbv + 128,
                                     new2c, bnB, bqB,
                                     bnsum0, bnsq0, bn0g, bn0b,
                                     bnA, bqA, bbng, bbnb);

  // classification heads + fused per-graph log_softmax (last-block pattern)
  k_cls2<<<1024,256,0,stream>>>(cur0, idx0P, new1c, idx1P, new2c,
                                pre2, cnt1, wl1, cpw,
                                bnsum0, bnsq0, bn0g, bn0b,
                                bnA, bqA, bbng, bbnb,
                                bnB, bqB, bbng + 128, bbnb + 128,
                                gW1, gb1, gW2, gb2, fW1, fb1, fW2, fb2,
                                yws, gcnt, (float*)d_out);
}